// Round 12
// baseline (377.998 us; speedup 1.0000x reference)
//
#include <hip/hip_runtime.h>
#include <hip/hip_bf16.h>
#include <math.h>

#define N_ATOMS 12000
#define K_NB 32
#define E_EDGES (N_ATOMS*K_NB)   // 384000
#define R_RES 1500
#define P_PAIRS 4096
#define LN_EPS 1e-5f

typedef __attribute__((ext_vector_type(8))) short short8;
typedef __attribute__((ext_vector_type(4))) float f32x4;
typedef __attribute__((ext_vector_type(4))) unsigned int u32x4;

__device__ __forceinline__ f32x4 splat4(float v){ f32x4 r = {v,v,v,v}; return r; }

__device__ __forceinline__ unsigned short f2bf(float f){
  unsigned u = __builtin_bit_cast(unsigned, f);
  u += 0x7FFF + ((u >> 16) & 1);   // RNE
  return (unsigned short)(u >> 16);
}

// 16-lane sum-to-all on the VALU pipe via DPP (no DS ops).
template<int CTRL>
__device__ __forceinline__ float dpp_add(float v){
  int x = __builtin_amdgcn_mov_dpp(__builtin_bit_cast(int, v), CTRL, 0xf, 0xf, true);
  return v + __builtin_bit_cast(float, x);
}
__device__ __forceinline__ float dpp16sum(float v){
  v = dpp_add<0xB1>(v);    // quad_perm [1,0,3,2]  : xor 1
  v = dpp_add<0x4E>(v);    // quad_perm [2,3,0,1]  : xor 2
  v = dpp_add<0x141>(v);   // row_half_mirror      : xor 4
  v = dpp_add<0x140>(v);   // row_mirror           : xor 8
  return v;
}

// atan2 for y >= 0 (y = |cross| here), abs err ~1e-5 rad.
__device__ __forceinline__ float fast_atan2(float y, float x){
  float ax = fabsf(x);
  float mn = fminf(ax, y);
  float mx = fmaxf(fmaxf(ax, y), 1e-30f);
  float r  = __builtin_amdgcn_rcpf(mx);
  r = r * (2.0f - mx * r);          // Newton: ~1e-7 rel
  float a = mn * r;                 // in [0,1]
  float s = a * a;
  float p = -0.0117212f;
  p = fmaf(p, s,  0.05265332f);
  p = fmaf(p, s, -0.11643287f);
  p = fmaf(p, s,  0.19354346f);
  p = fmaf(p, s, -0.33262347f);
  p = fmaf(p, s,  0.99997726f);
  p = p * a;
  p = (y > ax) ? (1.57079632679f - p) : p;
  p = (x < 0.f) ? (3.14159265359f - p) : p;
  return p;
}

__device__ __forceinline__ float angle3(float ax,float ay,float az,
                                        float bx,float by,float bz){
  float cx = ay*bz - az*by;
  float cy = az*bx - ax*bz;
  float cz = ax*by - ay*bx;
  float cn = sqrtf(cx*cx + cy*cy + cz*cz);
  float dt = ax*bx + ay*by + az*bz;
  return fast_atan2(cn, dt);
}

// ---------------------------------------------------------------------------
// K1 (merged): blocks x<1500 do per-edge PPF+MLP1+LN -> a_rec; extra blocks
// (x>=1500) pack atom_w/res_w f32 -> bf16 [K/32][512][32].
// grid: (1500+299, 3, 2), block 256.
// ---------------------------------------------------------------------------
__global__ __launch_bounds__(256) void geom_wpack_kernel(
    const float* __restrict__ pos_A, const float* __restrict__ nrm_A,
    const float* __restrict__ pos_B, const float* __restrict__ nrm_B,
    const int* __restrict__ edges_A, const int* __restrict__ edges_B,
    const float* __restrict__ w1, const float* __restrict__ b1,
    const float* __restrict__ g1, const float* __restrict__ be1,
    unsigned short* __restrict__ a_rec,
    const float* __restrict__ atom_w, const float* __restrict__ res_w,
    unsigned short* __restrict__ wpA, unsigned short* __restrict__ wpB)
{
  const int bx = blockIdx.x;
  const int r = blockIdx.y;
  const int side = blockIdx.z;

  if (bx >= 1500) {
    int fb = (r*2 + side)*299 + (bx - 1500);
    if (fb < 768) {                       // atom_w: 384*512 = 768 blocks
      int idx = fb*256 + threadIdx.x;
      int k = idx >> 9, n = idx & 511;
      wpA[(size_t)(k>>5)*512*32 + n*32 + (k&31)] = f2bf(atom_w[idx]);
    } else if (fb < 1792) {               // res_w: 512*512 = 1024 blocks
      int idx = (fb - 768)*256 + threadIdx.x;
      int k = idx >> 9, n = idx & 511;
      wpB[(size_t)(k>>5)*512*32 + n*32 + (k&31)] = f2bf(res_w[idx]);
    }
    return;
  }

  const float* __restrict__ pos = side ? pos_B : pos_A;
  const float* __restrict__ nrm = side ? nrm_B : nrm_A;
  const int* __restrict__ edges = (side ? edges_B : edges_A) + r*(2*E_EDGES);

  const int e = bx*256 + threadIdx.x;
  const int src = edges[e];
  const int dst = e >> 5;

  float psx = pos[src*3+0], psy = pos[src*3+1], psz = pos[src*3+2];
  float pdx = pos[dst*3+0], pdy = pos[dst*3+1], pdz = pos[dst*3+2];
  float dx = psx-pdx, dy = psy-pdy, dz = psz-pdz;
  float nix = nrm[dst*3+0], niy = nrm[dst*3+1], niz = nrm[dst*3+2];
  float njx = nrm[src*3+0], njy = nrm[src*3+1], njz = nrm[src*3+2];

  float f0 = sqrtf(dx*dx + dy*dy + dz*dz);
  float f1 = angle3(nix,niy,niz, dx,dy,dz);
  float f2 = angle3(njx,njy,njz, dx,dy,dz);
  float f3 = angle3(nix,niy,niz, njx,njy,njz);

  const float* w1r  = w1 + r*16;
  const float* b1r  = b1 + r*4;
  const float* g1r  = g1 + r*4;
  const float* be1r = be1 + r*4;
  float h[4]; float s1 = 0.f;
  #pragma unroll
  for (int j = 0; j < 4; ++j) {
    float t = b1r[j] + f0*w1r[j] + f1*w1r[4+j] + f2*w1r[8+j] + f3*w1r[12+j];
    t = fmaxf(t, 0.f);
    h[j] = t; s1 += t;
  }
  float mu1 = s1*0.25f;
  float v1 = 0.f;
  #pragma unroll
  for (int j = 0; j < 4; ++j) { float d = h[j]-mu1; v1 += d*d; }
  float inv1 = rsqrtf(v1*0.25f + LN_EPS);
  float a0 = g1r[0]*(h[0]-mu1)*inv1 + be1r[0];
  float a1 = g1r[1]*(h[1]-mu1)*inv1 + be1r[1];
  float a2 = g1r[2]*(h[2]-mu1)*inv1 + be1r[2];
  float a3 = g1r[3]*(h[3]-mu1)*inv1 + be1r[3];

  ushort4 rec;
  rec.x = f2bf(a0); rec.y = f2bf(a1); rec.z = f2bf(a2); rec.w = f2bf(a3);
  *(ushort4*)(a_rec + ((size_t)(side*3+r)*E_EDGES + e)*4) = rec;
}

// ---------------------------------------------------------------------------
// K2: layer2 (4->128) via MFMA 16x16x32 bf16 + relu + per-edge LN + node max.
// EXACT R9 config (VGPR 64, scalar stats + DPP reduction, no launch-bounds
// cap). Packed-f32 epilogue regressed twice (R7, R11: VGPR 124+, occ 20%).
// grid: (N/32, 3, 2), block 256 (4 waves), wave = 8 nodes looped.
// ---------------------------------------------------------------------------
__global__ __launch_bounds__(256) void edge_gemm_kernel(
    const unsigned short* __restrict__ a_rec,
    const float* __restrict__ w2, const float* __restrict__ b2,
    const float* __restrict__ g2, const float* __restrict__ be2,
    unsigned short* __restrict__ feats_A, unsigned short* __restrict__ feats_B)
{
  const int r = blockIdx.y;
  const int side = blockIdx.z;
  unsigned short* __restrict__ feats = side ? feats_B : feats_A;

  const int tid  = threadIdx.x;
  const int wv   = tid >> 6;
  const int lane = tid & 63;
  const int l15  = lane & 15;
  const bool live = (lane < 16);

  const float* __restrict__ w2r = w2 + r*512;    // [4][128]

  short8 bfrag[8];
  float bias[8], gg[8], ee[8];
  #pragma unroll
  for (int ct = 0; ct < 8; ++ct) {
    int n = ct*16 + l15;
    float v0 = w2r[0*128+n], v1 = w2r[1*128+n];
    float v2 = w2r[2*128+n], v3 = w2r[3*128+n];
    short8 bf = {0,0,0,0,0,0,0,0};
    bf[0] = live ? (short)f2bf(v0) : (short)0;
    bf[1] = live ? (short)f2bf(v1) : (short)0;
    bf[2] = live ? (short)f2bf(v2) : (short)0;
    bf[3] = live ? (short)f2bf(v3) : (short)0;
    bfrag[ct] = bf;
    bias[ct] = b2[r*128+n];
    gg[ct]   = g2[r*128+n];
    ee[ct]   = be2[r*128+n];
  }

  const int node0 = blockIdx.x*32 + wv*8;
  const unsigned short* __restrict__ arp0 =
      a_rec + ((size_t)(side*3+r)*E_EDGES + (size_t)node0*32)*4;

  const f32x4 zero4 = splat4(0.f);

  for (int nd = 0; nd < 8; ++nd) {
    const unsigned short* arp = arp0 + nd*32*4;
    ushort4 a4_0 = *(const ushort4*)(arp + (l15)*4);
    ushort4 a4_1 = *(const ushort4*)(arp + (16 + l15)*4);

    float nodemax[8];
    #pragma unroll
    for (int ct = 0; ct < 8; ++ct) nodemax[ct] = -3.4e38f;

    #pragma unroll
    for (int rt = 0; rt < 2; ++rt) {
      ushort4 a4 = rt ? a4_1 : a4_0;
      unsigned alo = (unsigned)a4.x | ((unsigned)a4.y << 16);
      unsigned ahi = (unsigned)a4.z | ((unsigned)a4.w << 16);
      alo = live ? alo : 0u;
      ahi = live ? ahi : 0u;
      u32x4 pk = {alo, ahi, 0u, 0u};
      short8 af = __builtin_bit_cast(short8, pk);

      f32x4 acc[8];
      #pragma unroll
      for (int ct = 0; ct < 8; ++ct)
        acc[ct] = __builtin_amdgcn_mfma_f32_16x16x32_bf16(af, bfrag[ct], zero4, 0, 0, 0);

      float p[4] = {0,0,0,0}, q[4] = {0,0,0,0};
      #pragma unroll
      for (int ct = 0; ct < 8; ++ct) {
        #pragma unroll
        for (int i = 0; i < 4; ++i) {
          float t = fmaxf(acc[ct][i] + bias[ct], 0.f);
          acc[ct][i] = t; p[i] += t; q[i] = fmaf(t, t, q[i]);
        }
      }
      #pragma unroll
      for (int i = 0; i < 4; ++i) {
        p[i] = dpp16sum(p[i]);
        q[i] = dpp16sum(q[i]);
      }
      float uu[4], vv[4];
      #pragma unroll
      for (int i = 0; i < 4; ++i) {
        float mu  = p[i]*(1.f/128.f);
        float var = fmaxf(q[i]*(1.f/128.f) - mu*mu, 0.f);
        float inv = rsqrtf(var + LN_EPS);
        uu[i] = inv; vv[i] = -mu*inv;
      }
      #pragma unroll
      for (int ct = 0; ct < 8; ++ct) {
        float vm = -3.4e38f;
        #pragma unroll
        for (int i = 0; i < 4; ++i) {
          float val = gg[ct]*fmaf(acc[ct][i], uu[i], vv[i]) + ee[ct];
          vm = fmaxf(vm, val);
        }
        nodemax[ct] = fmaxf(nodemax[ct], vm);
      }
    }

    #pragma unroll
    for (int ct = 0; ct < 8; ++ct) {
      float vm = nodemax[ct];
      vm = fmaxf(vm, __shfl_xor(vm, 16, 64));
      vm = fmaxf(vm, __shfl_xor(vm, 32, 64));
      nodemax[ct] = vm;
    }

    if (live) {
      const int gnode = node0 + nd;
      #pragma unroll
      for (int ct = 0; ct < 8; ++ct)
        feats[(size_t)gnode*384 + r*128 + ct*16 + l15] = f2bf(nodemax[ct]);
    }
  }
}

// ---------------------------------------------------------------------------
// K3: atom layer GEMM+LN with REGISTER-PREFETCH double buffering: chunk k+1's
// A/B global loads issue during chunk k's MFMA phase, so the vmcnt drain
// before the staging barrier is already satisfied (was: load -> immediate
// wait -> barrier, fully exposed per chunk).
// grid: (ceil(nrows/64), 2), block 256.
// ---------------------------------------------------------------------------
__global__ __launch_bounds__(256) void gemm_ln_kernel(
    const unsigned short* __restrict__ x_A, const unsigned short* __restrict__ x_B,
    const unsigned short* __restrict__ wp,
    const float* __restrict__ b, const float* __restrict__ g,
    const float* __restrict__ be,
    float* __restrict__ out_A, float* __restrict__ out_B,
    int nrows, int Kdim)
{
  const unsigned short* __restrict__ x = blockIdx.y ? x_B : x_A;
  float* __restrict__ out = blockIdx.y ? out_B : out_A;

  __shared__ __align__(16) unsigned short sA[64*40];    // 5 KB
  __shared__ __align__(16) unsigned short sB[512*40];   // 40 KB
  __shared__ float sb[512], sg[512], sbe[512];          // 6 KB

  const int tid  = threadIdx.x;
  const int wv   = tid >> 6;
  const int lane = tid & 63;
  const int l15  = lane & 15;
  const int quad = lane >> 4;
  const int rbase = blockIdx.x * 64;

  sb[tid]      = b[tid];    sb[tid+256]  = b[tid+256];
  sg[tid]      = g[tid];    sg[tid+256]  = g[tid+256];
  sbe[tid]     = be[tid];   sbe[tid+256] = be[tid+256];

  const f32x4 zero4 = splat4(0.f);
  f32x4 acc[32];
  #pragma unroll
  for (int ct = 0; ct < 32; ++ct) acc[ct] = zero4;

  const int nchunk = Kdim >> 5;
  const int arow = tid >> 2, apart = tid & 3;
  int agr = rbase + arow; if (agr >= nrows) agr = nrows - 1;
  const unsigned short* aptr = x + (size_t)agr*Kdim + apart*8;

  // prefetch chunk 0 into registers
  float4 breg[8];
  {
    const float4* src = (const float4*)(wp);
    #pragma unroll
    for (int i = 0; i < 8; ++i) breg[i] = src[tid + i*256];
  }
  float4 areg = *(const float4*)(aptr);

  for (int kc = 0; kc < nchunk; ++kc) {
    // write staged registers to LDS
    *(float4*)&sA[arow*40 + apart*8] = areg;
    #pragma unroll
    for (int i = 0; i < 8; ++i) {
      int fi = tid + i*256;
      int n = fi >> 2, part = fi & 3;
      *(float4*)&sB[n*40 + part*8] = breg[i];
    }
    __syncthreads();
    // prefetch next chunk (completes during MFMA phase)
    if (kc + 1 < nchunk) {
      const float4* src = (const float4*)(wp + (size_t)(kc+1)*512*32);
      #pragma unroll
      for (int i = 0; i < 8; ++i) breg[i] = src[tid + i*256];
      areg = *(const float4*)(aptr + (kc+1)*32);
    }
    short8 af = *(short8*)&sA[(wv*16 + l15)*40 + quad*8];
    #pragma unroll
    for (int ct = 0; ct < 32; ++ct) {
      short8 bf = *(short8*)&sB[(ct*16 + l15)*40 + quad*8];
      acc[ct] = __builtin_amdgcn_mfma_f32_16x16x32_bf16(af, bf, acc[ct], 0, 0, 0);
    }
    __syncthreads();
  }

  f32x4 p = zero4, q = zero4;
  #pragma unroll
  for (int ct = 0; ct < 32; ++ct) {
    f32x4 t = __builtin_elementwise_max(acc[ct] + splat4(sb[ct*16 + l15]), zero4);
    acc[ct] = t;
    p += t;
    q += t * t;
  }
  #pragma unroll
  for (int i = 0; i < 4; ++i) {
    p[i] = dpp16sum(p[i]);
    q[i] = dpp16sum(q[i]);
  }
  f32x4 mu4  = p * splat4(1.f/512.f);
  f32x4 var4 = __builtin_elementwise_max(q * splat4(1.f/512.f) - mu4*mu4, zero4);
  f32x4 uu, vv;
  #pragma unroll
  for (int i = 0; i < 4; ++i) {
    float inv = rsqrtf(var4[i] + LN_EPS);
    uu[i] = inv; vv[i] = -mu4[i]*inv;
  }
  const int row0 = rbase + wv*16 + quad*4;
  #pragma unroll
  for (int ct = 0; ct < 32; ++ct) {
    int gcol = ct*16 + l15;
    f32x4 v = acc[ct]*uu + vv;
    v = splat4(sg[gcol])*v + splat4(sbe[gcol]);
    #pragma unroll
    for (int i = 0; i < 4; ++i) {
      int grow = row0 + i;
      if (grow < nrows)
        out[(size_t)grow*512 + gcol] = v[i];
    }
  }
}

// ---------------------------------------------------------------------------
// K4: res layer with fused residue-max A-staging + register-prefetch double
// buffering (only 48 blocks -> latency fully exposed without it).
// grid: (ceil(R/64), 2), block 256.
// ---------------------------------------------------------------------------
__global__ __launch_bounds__(256) void gemm_ln_res_kernel(
    const float* __restrict__ ax_A, const float* __restrict__ ax_B,
    const unsigned short* __restrict__ wp,
    const float* __restrict__ b, const float* __restrict__ g,
    const float* __restrict__ be,
    float* __restrict__ out_A, float* __restrict__ out_B)
{
  const float* __restrict__ ax = blockIdx.y ? ax_B : ax_A;
  float* __restrict__ out = blockIdx.y ? out_B : out_A;

  __shared__ __align__(16) unsigned short sA[64*40];    // 5 KB
  __shared__ __align__(16) unsigned short sB[512*40];   // 40 KB
  __shared__ float sb[512], sg[512], sbe[512];          // 6 KB

  const int tid  = threadIdx.x;
  const int wv   = tid >> 6;
  const int lane = tid & 63;
  const int l15  = lane & 15;
  const int quad = lane >> 4;
  const int rbase = blockIdx.x * 64;

  sb[tid]      = b[tid];    sb[tid+256]  = b[tid+256];
  sg[tid]      = g[tid];    sg[tid+256]  = g[tid+256];
  sbe[tid]     = be[tid];   sbe[tid+256] = be[tid+256];

  const f32x4 zero4 = splat4(0.f);
  f32x4 acc[32];
  #pragma unroll
  for (int ct = 0; ct < 32; ++ct) acc[ct] = zero4;

  const int arow = tid >> 2, apart = tid & 3;
  int rres = rbase + arow; if (rres >= R_RES) rres = R_RES - 1;
  const float* abase = ax + (size_t)rres*8*512 + apart*8;

  // residue-max of chunk kc into bf16x8 regs
  auto amax_chunk = [&](int kc, ushort4& o0, ushort4& o1) {
    const float* ap = abase + kc*32;
    float4 m0 = *(const float4*)(ap);
    float4 m1 = *(const float4*)(ap + 4);
    #pragma unroll
    for (int a = 1; a < 8; ++a) {
      float4 v0 = *(const float4*)(ap + (size_t)a*512);
      float4 v1 = *(const float4*)(ap + (size_t)a*512 + 4);
      m0.x = fmaxf(m0.x, v0.x); m0.y = fmaxf(m0.y, v0.y);
      m0.z = fmaxf(m0.z, v0.z); m0.w = fmaxf(m0.w, v0.w);
      m1.x = fmaxf(m1.x, v1.x); m1.y = fmaxf(m1.y, v1.y);
      m1.z = fmaxf(m1.z, v1.z); m1.w = fmaxf(m1.w, v1.w);
    }
    o0.x = f2bf(m0.x); o0.y = f2bf(m0.y); o0.z = f2bf(m0.z); o0.w = f2bf(m0.w);
    o1.x = f2bf(m1.x); o1.y = f2bf(m1.y); o1.z = f2bf(m1.z); o1.w = f2bf(m1.w);
  };

  float4 breg[8];
  {
    const float4* src = (const float4*)(wp);
    #pragma unroll
    for (int i = 0; i < 8; ++i) breg[i] = src[tid + i*256];
  }
  ushort4 a0, a1;
  amax_chunk(0, a0, a1);

  for (int kc = 0; kc < 16; ++kc) {
    *(ushort4*)&sA[arow*40 + apart*8]     = a0;
    *(ushort4*)&sA[arow*40 + apart*8 + 4] = a1;
    #pragma unroll
    for (int i = 0; i < 8; ++i) {
      int fi = tid + i*256;
      int n = fi >> 2, part = fi & 3;
      *(float4*)&sB[n*40 + part*8] = breg[i];
    }
    __syncthreads();
    if (kc + 1 < 16) {
      const float4* src = (const float4*)(wp + (size_t)(kc+1)*512*32);
      #pragma unroll
      for (int i = 0; i < 8; ++i) breg[i] = src[tid + i*256];
      amax_chunk(kc+1, a0, a1);
    }
    short8 af = *(short8*)&sA[(wv*16 + l15)*40 + quad*8];
    #pragma unroll
    for (int ct = 0; ct < 32; ++ct) {
      short8 bf = *(short8*)&sB[(ct*16 + l15)*40 + quad*8];
      acc[ct] = __builtin_amdgcn_mfma_f32_16x16x32_bf16(af, bf, acc[ct], 0, 0, 0);
    }
    __syncthreads();
  }

  f32x4 p = zero4, q = zero4;
  #pragma unroll
  for (int ct = 0; ct < 32; ++ct) {
    f32x4 t = __builtin_elementwise_max(acc[ct] + splat4(sb[ct*16 + l15]), zero4);
    acc[ct] = t;
    p += t;
    q += t * t;
  }
  #pragma unroll
  for (int i = 0; i < 4; ++i) {
    p[i] = dpp16sum(p[i]);
    q[i] = dpp16sum(q[i]);
  }
  f32x4 mu4  = p * splat4(1.f/512.f);
  f32x4 var4 = __builtin_elementwise_max(q * splat4(1.f/512.f) - mu4*mu4, zero4);
  f32x4 uu, vv;
  #pragma unroll
  for (int i = 0; i < 4; ++i) {
    float inv = rsqrtf(var4[i] + LN_EPS);
    uu[i] = inv; vv[i] = -mu4[i]*inv;
  }
  const int row0 = rbase + wv*16 + quad*4;
  #pragma unroll
  for (int ct = 0; ct < 32; ++ct) {
    int gcol = ct*16 + l15;
    f32x4 v = acc[ct]*uu + vv;
    v = splat4(sg[gcol])*v + splat4(sbe[gcol]);
    #pragma unroll
    for (int i = 0; i < 4; ++i) {
      int grow = row0 + i;
      if (grow < R_RES)
        out[(size_t)grow*512 + gcol] = v[i];
    }
  }
}

// ---------------------------------------------------------------------------
// K5: out[p] = sigmoid((resx_A[src[p]] - resx_B[tgt[p]]) . lin_w + b)
// 8 lanes per pair (128 blocks; was 16 — a hidden ~40us kernel before R11).
// ---------------------------------------------------------------------------
__global__ __launch_bounds__(256) void final_kernel(
    const float* __restrict__ resx_A, const float* __restrict__ resx_B,
    const int* __restrict__ src_idx, const int* __restrict__ tgt_idx,
    const float* __restrict__ lin_w, const float* __restrict__ lin_b,
    float* __restrict__ outp)
{
  int idx = blockIdx.x*256 + threadIdx.x;
  int p  = idx >> 3;
  int l8 = idx & 7;
  if (p >= P_PAIRS) return;
  const float4* xa = (const float4*)(resx_A + (size_t)src_idx[p]*512) + l8;
  const float4* xb = (const float4*)(resx_B + (size_t)tgt_idx[p]*512) + l8;
  const float4* wv = (const float4*)lin_w + l8;
  float acc = 0.f;
  #pragma unroll
  for (int i = 0; i < 16; ++i) {
    float4 a = xa[i*8], b = xb[i*8], w = wv[i*8];
    acc += (a.x-b.x)*w.x + (a.y-b.y)*w.y + (a.z-b.z)*w.z + (a.w-b.w)*w.w;
  }
  acc += __shfl_xor(acc, 1, 64);
  acc += __shfl_xor(acc, 2, 64);
  acc += __shfl_xor(acc, 4, 64);
  if (l8 == 0) {
    acc += lin_b[0];
    outp[p] = 1.f/(1.f + expf(-acc));
  }
}

extern "C" void kernel_launch(void* const* d_in, const int* in_sizes, int n_in,
                              void* d_out, int out_size, void* d_ws, size_t ws_size,
                              hipStream_t stream)
{
  const float* pos_A   = (const float*)d_in[0];
  const float* nrm_A   = (const float*)d_in[1];
  const float* pos_B   = (const float*)d_in[2];
  const float* nrm_B   = (const float*)d_in[3];
  const int*   edges_A = (const int*)d_in[4];
  const int*   edges_B = (const int*)d_in[5];
  const int*   src_idx = (const int*)d_in[8];
  const int*   tgt_idx = (const int*)d_in[9];
  const float* conv_w1  = (const float*)d_in[11];
  const float* conv_b1  = (const float*)d_in[12];
  const float* conv_g1  = (const float*)d_in[13];
  const float* conv_be1 = (const float*)d_in[14];
  const float* conv_w2  = (const float*)d_in[15];
  const float* conv_b2  = (const float*)d_in[16];
  const float* conv_g2  = (const float*)d_in[17];
  const float* conv_be2 = (const float*)d_in[18];
  const float* atom_w   = (const float*)d_in[19];
  const float* atom_b   = (const float*)d_in[20];
  const float* atom_g   = (const float*)d_in[21];
  const float* atom_be  = (const float*)d_in[22];
  const float* res_w    = (const float*)d_in[23];
  const float* res_b    = (const float*)d_in[24];
  const float* res_g    = (const float*)d_in[25];
  const float* res_be   = (const float*)d_in[26];
  const float* lin1_w   = (const float*)d_in[27];
  const float* lin1_b   = (const float*)d_in[28];

  unsigned short* feats_A = (unsigned short*)d_ws;                 // 12000*384 bf16
  unsigned short* feats_B = feats_A + (size_t)N_ATOMS*384;
  float* atomx_A = (float*)(feats_B + (size_t)N_ATOMS*384);        // 12000*512 f32
  float* atomx_B = atomx_A + (size_t)N_ATOMS*512;
  float* resx_A  = atomx_B + (size_t)N_ATOMS*512;                  // 1500*512 f32
  float* resx_B  = resx_A + (size_t)R_RES*512;
  unsigned short* a_rec = (unsigned short*)(resx_B + (size_t)R_RES*512); // 6*E*4 bf16
  unsigned short* wpA   = a_rec + (size_t)6*E_EDGES*4;             // 12*512*32 bf16
  unsigned short* wpB   = wpA + (size_t)384*512;                   // 16*512*32 bf16

  dim3 gE(1500 + 299, 3, 2);
  geom_wpack_kernel<<<gE, 256, 0, stream>>>(pos_A, nrm_A, pos_B, nrm_B,
      edges_A, edges_B, conv_w1, conv_b1, conv_g1, conv_be1, a_rec,
      atom_w, res_w, wpA, wpB);

  dim3 gG(N_ATOMS/32, 3, 2);
  edge_gemm_kernel<<<gG, 256, 0, stream>>>(a_rec,
      conv_w2, conv_b2, conv_g2, conv_be2, feats_A, feats_B);

  dim3 gAtom((N_ATOMS + 63)/64, 2);
  gemm_ln_kernel<<<gAtom, 256, 0, stream>>>(feats_A, feats_B, wpA,
      atom_b, atom_g, atom_be, atomx_A, atomx_B, N_ATOMS, 384);

  dim3 gRes((R_RES + 63)/64, 2);
  gemm_ln_res_kernel<<<gRes, 256, 0, stream>>>(atomx_A, atomx_B, wpB,
      res_b, res_g, res_be, resx_A, resx_B);

  final_kernel<<<(P_PAIRS*8 + 255)/256, 256, 0, stream>>>(resx_A, resx_B,
      src_idx, tgt_idx, lin1_w, lin1_b, (float*)d_out);
}

// Round 13
// 324.029 us; speedup vs baseline: 1.1666x; 1.1666x over previous
//
#include <hip/hip_runtime.h>
#include <hip/hip_bf16.h>
#include <math.h>

#define N_ATOMS 12000
#define K_NB 32
#define E_EDGES (N_ATOMS*K_NB)   // 384000
#define R_RES 1500
#define P_PAIRS 4096
#define LN_EPS 1e-5f

typedef __attribute__((ext_vector_type(8))) short short8;
typedef __attribute__((ext_vector_type(4))) float f32x4;
typedef __attribute__((ext_vector_type(4))) unsigned int u32x4;

__device__ __forceinline__ f32x4 splat4(float v){ f32x4 r = {v,v,v,v}; return r; }

__device__ __forceinline__ unsigned short f2bf(float f){
  unsigned u = __builtin_bit_cast(unsigned, f);
  u += 0x7FFF + ((u >> 16) & 1);   // RNE
  return (unsigned short)(u >> 16);
}

// 16-lane sum-to-all on the VALU pipe via DPP (no DS ops).
template<int CTRL>
__device__ __forceinline__ float dpp_add(float v){
  int x = __builtin_amdgcn_mov_dpp(__builtin_bit_cast(int, v), CTRL, 0xf, 0xf, true);
  return v + __builtin_bit_cast(float, x);
}
__device__ __forceinline__ float dpp16sum(float v){
  v = dpp_add<0xB1>(v);    // quad_perm [1,0,3,2]  : xor 1
  v = dpp_add<0x4E>(v);    // quad_perm [2,3,0,1]  : xor 2
  v = dpp_add<0x141>(v);   // row_half_mirror      : xor 4
  v = dpp_add<0x140>(v);   // row_mirror           : xor 8
  return v;
}

// atan2 for y >= 0 (y = |cross| here), abs err ~1e-5 rad.
__device__ __forceinline__ float fast_atan2(float y, float x){
  float ax = fabsf(x);
  float mn = fminf(ax, y);
  float mx = fmaxf(fmaxf(ax, y), 1e-30f);
  float r  = __builtin_amdgcn_rcpf(mx);
  r = r * (2.0f - mx * r);          // Newton: ~1e-7 rel
  float a = mn * r;                 // in [0,1]
  float s = a * a;
  float p = -0.0117212f;
  p = fmaf(p, s,  0.05265332f);
  p = fmaf(p, s, -0.11643287f);
  p = fmaf(p, s,  0.19354346f);
  p = fmaf(p, s, -0.33262347f);
  p = fmaf(p, s,  0.99997726f);
  p = p * a;
  p = (y > ax) ? (1.57079632679f - p) : p;
  p = (x < 0.f) ? (3.14159265359f - p) : p;
  return p;
}

__device__ __forceinline__ float angle3(float ax,float ay,float az,
                                        float bx,float by,float bz){
  float cx = ay*bz - az*by;
  float cy = az*bx - ax*bz;
  float cz = ax*by - ay*bx;
  float cn = sqrtf(cx*cx + cy*cy + cz*cz);
  float dt = ax*bx + ay*by + az*bz;
  return fast_atan2(cn, dt);
}

// ---------------------------------------------------------------------------
// K0: pack f32 weights [K][512] -> bf16 [K/32][512][32].
// ---------------------------------------------------------------------------
__global__ __launch_bounds__(256) void wpack_kernel(
    const float* __restrict__ w, unsigned short* __restrict__ wp, int Kdim)
{
  int idx = blockIdx.x*256 + threadIdx.x;
  if (idx >= Kdim*512) return;
  int k = idx >> 9, n = idx & 511;
  wp[(size_t)(k>>5)*512*32 + n*32 + (k&31)] = f2bf(w[idx]);
}

// ---------------------------------------------------------------------------
// K1 (wave-fused edge stage): each wave owns 8 nodes, processed as 4 windows
// of 2 nodes (64 edges). Per window: each lane computes ITS edge's PPF +
// MLP(4->4)+LN (no barriers, no a_rec round-trip — 36 MB of HBM W+R gone;
// R5's block-level fusion failed on barrier coupling, this is wave-local).
// A-fragments assembled from the computing lanes via __shfl (bpermute).
// MFMA + relu + per-edge LN (DPP stats) + node max = R9's proven epilogue
// (VGPR 64-profile; packed-f32 epilogue regressed twice: R7, R11).
// grid: (N/32, 3, 2), block 256 (4 waves).
// ---------------------------------------------------------------------------
__global__ __launch_bounds__(256) void edge_fused_kernel(
    const float* __restrict__ pos_A, const float* __restrict__ nrm_A,
    const float* __restrict__ pos_B, const float* __restrict__ nrm_B,
    const int* __restrict__ edges_A, const int* __restrict__ edges_B,
    const float* __restrict__ w1, const float* __restrict__ b1,
    const float* __restrict__ g1, const float* __restrict__ be1,
    const float* __restrict__ w2, const float* __restrict__ b2,
    const float* __restrict__ g2, const float* __restrict__ be2,
    unsigned short* __restrict__ feats_A, unsigned short* __restrict__ feats_B)
{
  const int r = blockIdx.y;
  const int side = blockIdx.z;
  const float* __restrict__ pos = side ? pos_B : pos_A;
  const float* __restrict__ nrm = side ? nrm_B : nrm_A;
  const int* __restrict__ edges = (side ? edges_B : edges_A) + r*(2*E_EDGES);
  unsigned short* __restrict__ feats = side ? feats_B : feats_A;

  const int tid  = threadIdx.x;
  const int wv   = tid >> 6;
  const int lane = tid & 63;
  const int l15  = lane & 15;
  const bool live = (lane < 16);

  const float* __restrict__ w1r  = w1  + r*16;
  const float* __restrict__ b1r  = b1  + r*4;
  const float* __restrict__ g1r  = g1  + r*4;
  const float* __restrict__ be1r = be1 + r*4;
  const float* __restrict__ w2r  = w2  + r*512;   // [4][128]

  // hoisted per-wave constants (amortized over 8 nodes)
  short8 bfrag[8];
  float bias[8], gg[8], ee[8];
  #pragma unroll
  for (int ct = 0; ct < 8; ++ct) {
    int n = ct*16 + l15;
    float v0 = w2r[0*128+n], v1 = w2r[1*128+n];
    float v2 = w2r[2*128+n], v3 = w2r[3*128+n];
    short8 bf = {0,0,0,0,0,0,0,0};
    bf[0] = live ? (short)f2bf(v0) : (short)0;
    bf[1] = live ? (short)f2bf(v1) : (short)0;
    bf[2] = live ? (short)f2bf(v2) : (short)0;
    bf[3] = live ? (short)f2bf(v3) : (short)0;
    bfrag[ct] = bf;
    bias[ct] = b2[r*128+n];
    gg[ct]   = g2[r*128+n];
    ee[ct]   = be2[r*128+n];
  }

  const int node0 = blockIdx.x*32 + wv*8;
  const f32x4 zero4 = splat4(0.f);

  for (int win = 0; win < 4; ++win) {
    // ---- geometry + layer1 for this window's 64 edges (one per lane) ----
    const int e = (node0 + win*2)*K_NB + lane;
    const int src = edges[e];
    const int dst = e >> 5;

    float psx = pos[src*3+0], psy = pos[src*3+1], psz = pos[src*3+2];
    float pdx = pos[dst*3+0], pdy = pos[dst*3+1], pdz = pos[dst*3+2];
    float dx = psx-pdx, dy = psy-pdy, dz = psz-pdz;
    float nix = nrm[dst*3+0], niy = nrm[dst*3+1], niz = nrm[dst*3+2];
    float njx = nrm[src*3+0], njy = nrm[src*3+1], njz = nrm[src*3+2];

    float f0 = sqrtf(dx*dx + dy*dy + dz*dz);
    float f1 = angle3(nix,niy,niz, dx,dy,dz);
    float f2 = angle3(njx,njy,njz, dx,dy,dz);
    float f3 = angle3(nix,niy,niz, njx,njy,njz);

    float h[4]; float s1 = 0.f;
    #pragma unroll
    for (int j = 0; j < 4; ++j) {
      float t = b1r[j] + f0*w1r[j] + f1*w1r[4+j] + f2*w1r[8+j] + f3*w1r[12+j];
      t = fmaxf(t, 0.f);
      h[j] = t; s1 += t;
    }
    float mu1 = s1*0.25f;
    float v1 = 0.f;
    #pragma unroll
    for (int j = 0; j < 4; ++j) { float d = h[j]-mu1; v1 += d*d; }
    float inv1 = rsqrtf(v1*0.25f + LN_EPS);
    float a0 = g1r[0]*(h[0]-mu1)*inv1 + be1r[0];
    float a1 = g1r[1]*(h[1]-mu1)*inv1 + be1r[1];
    float a2 = g1r[2]*(h[2]-mu1)*inv1 + be1r[2];
    float a3 = g1r[3]*(h[3]-mu1)*inv1 + be1r[3];

    // same bf16 packing point as the split pipeline -> bit-identical output
    unsigned alo = (unsigned)f2bf(a0) | ((unsigned)f2bf(a1) << 16);
    unsigned ahi = (unsigned)f2bf(a2) | ((unsigned)f2bf(a3) << 16);

    // ---- 2 nodes' MFMA + LN + node-max ----
    #pragma unroll
    for (int nd2 = 0; nd2 < 2; ++nd2) {
      float nodemax[8];
      #pragma unroll
      for (int ct = 0; ct < 8; ++ct) nodemax[ct] = -3.4e38f;

      #pragma unroll
      for (int rt = 0; rt < 2; ++rt) {
        const int srcl = nd2*32 + rt*16 + l15;   // window-local edge lane
        unsigned palo = __shfl(alo, srcl, 64);
        unsigned pahi = __shfl(ahi, srcl, 64);
        palo = live ? palo : 0u;
        pahi = live ? pahi : 0u;
        u32x4 pk = {palo, pahi, 0u, 0u};
        short8 af = __builtin_bit_cast(short8, pk);

        f32x4 acc[8];
        #pragma unroll
        for (int ct = 0; ct < 8; ++ct)
          acc[ct] = __builtin_amdgcn_mfma_f32_16x16x32_bf16(af, bfrag[ct], zero4, 0, 0, 0);

        float p[4] = {0,0,0,0}, q[4] = {0,0,0,0};
        #pragma unroll
        for (int ct = 0; ct < 8; ++ct) {
          #pragma unroll
          for (int i = 0; i < 4; ++i) {
            float t = fmaxf(acc[ct][i] + bias[ct], 0.f);
            acc[ct][i] = t; p[i] += t; q[i] = fmaf(t, t, q[i]);
          }
        }
        #pragma unroll
        for (int i = 0; i < 4; ++i) {
          p[i] = dpp16sum(p[i]);
          q[i] = dpp16sum(q[i]);
        }
        float uu[4], vv[4];
        #pragma unroll
        for (int i = 0; i < 4; ++i) {
          float mu  = p[i]*(1.f/128.f);
          float var = fmaxf(q[i]*(1.f/128.f) - mu*mu, 0.f);
          float inv = rsqrtf(var + LN_EPS);
          uu[i] = inv; vv[i] = -mu*inv;
        }
        #pragma unroll
        for (int ct = 0; ct < 8; ++ct) {
          float vm = -3.4e38f;
          #pragma unroll
          for (int i = 0; i < 4; ++i) {
            float val = gg[ct]*fmaf(acc[ct][i], uu[i], vv[i]) + ee[ct];
            vm = fmaxf(vm, val);
          }
          nodemax[ct] = fmaxf(nodemax[ct], vm);
        }
      }

      #pragma unroll
      for (int ct = 0; ct < 8; ++ct) {
        float vm = nodemax[ct];
        vm = fmaxf(vm, __shfl_xor(vm, 16, 64));
        vm = fmaxf(vm, __shfl_xor(vm, 32, 64));
        nodemax[ct] = vm;
      }

      if (live) {
        const int gnode = node0 + win*2 + nd2;
        #pragma unroll
        for (int ct = 0; ct < 8; ++ct)
          feats[(size_t)gnode*384 + r*128 + ct*16 + l15] = f2bf(nodemax[ct]);
      }
    }
  }
}

// ---------------------------------------------------------------------------
// K3: atom layer GEMM+LN. R11-EXACT structure (single staging per chunk, no
// register prefetch — R12's prefetch cost +57us via VGPR/occupancy).
// grid: (ceil(nrows/64), 2), block 256.
// ---------------------------------------------------------------------------
__global__ __launch_bounds__(256) void gemm_ln_kernel(
    const unsigned short* __restrict__ x_A, const unsigned short* __restrict__ x_B,
    const unsigned short* __restrict__ wp,
    const float* __restrict__ b, const float* __restrict__ g,
    const float* __restrict__ be,
    float* __restrict__ out_A, float* __restrict__ out_B,
    int nrows, int Kdim)
{
  const unsigned short* __restrict__ x = blockIdx.y ? x_B : x_A;
  float* __restrict__ out = blockIdx.y ? out_B : out_A;

  __shared__ __align__(16) unsigned short sA[64*40];    // 5 KB
  __shared__ __align__(16) unsigned short sB[512*40];   // 40 KB
  __shared__ float sb[512], sg[512], sbe[512];          // 6 KB

  const int tid  = threadIdx.x;
  const int wv   = tid >> 6;
  const int lane = tid & 63;
  const int l15  = lane & 15;
  const int quad = lane >> 4;
  const int rbase = blockIdx.x * 64;

  sb[tid]      = b[tid];    sb[tid+256]  = b[tid+256];
  sg[tid]      = g[tid];    sg[tid+256]  = g[tid+256];
  sbe[tid]     = be[tid];   sbe[tid+256] = be[tid+256];

  const f32x4 zero4 = splat4(0.f);
  f32x4 acc[32];
  #pragma unroll
  for (int ct = 0; ct < 32; ++ct) acc[ct] = zero4;

  const int nchunk = Kdim >> 5;
  const int arow = tid >> 2, apart = tid & 3;
  int agr = rbase + arow; if (agr >= nrows) agr = nrows - 1;
  const unsigned short* aptr = x + (size_t)agr*Kdim + apart*8;

  for (int kc = 0; kc < nchunk; ++kc) {
    __syncthreads();
    *(float4*)&sA[arow*40 + apart*8] = *(const float4*)(aptr + kc*32);
    {
      const float4* src = (const float4*)(wp + (size_t)kc*512*32);
      #pragma unroll
      for (int i = 0; i < 8; ++i) {
        int fi = tid + i*256;
        int n = fi >> 2, part = fi & 3;
        *(float4*)&sB[n*40 + part*8] = src[fi];
      }
    }
    __syncthreads();
    short8 af = *(short8*)&sA[(wv*16 + l15)*40 + quad*8];
    #pragma unroll
    for (int ct = 0; ct < 32; ++ct) {
      short8 bf = *(short8*)&sB[(ct*16 + l15)*40 + quad*8];
      acc[ct] = __builtin_amdgcn_mfma_f32_16x16x32_bf16(af, bf, acc[ct], 0, 0, 0);
    }
  }

  f32x4 p = zero4, q = zero4;
  #pragma unroll
  for (int ct = 0; ct < 32; ++ct) {
    f32x4 t = __builtin_elementwise_max(acc[ct] + splat4(sb[ct*16 + l15]), zero4);
    acc[ct] = t;
    p += t;
    q += t * t;
  }
  #pragma unroll
  for (int i = 0; i < 4; ++i) {
    p[i] = dpp16sum(p[i]);
    q[i] = dpp16sum(q[i]);
  }
  f32x4 mu4  = p * splat4(1.f/512.f);
  f32x4 var4 = __builtin_elementwise_max(q * splat4(1.f/512.f) - mu4*mu4, zero4);
  f32x4 uu, vv;
  #pragma unroll
  for (int i = 0; i < 4; ++i) {
    float inv = rsqrtf(var4[i] + LN_EPS);
    uu[i] = inv; vv[i] = -mu4[i]*inv;
  }
  const int row0 = rbase + wv*16 + quad*4;
  #pragma unroll
  for (int ct = 0; ct < 32; ++ct) {
    int gcol = ct*16 + l15;
    f32x4 v = acc[ct]*uu + vv;
    v = splat4(sg[gcol])*v + splat4(sbe[gcol]);
    #pragma unroll
    for (int i = 0; i < 4; ++i) {
      int grow = row0 + i;
      if (grow < nrows)
        out[(size_t)grow*512 + gcol] = v[i];
    }
  }
}

// ---------------------------------------------------------------------------
// K4: res layer with fused residue-max A-staging. R11-EXACT (no prefetch).
// grid: (ceil(R/64), 2), block 256.
// ---------------------------------------------------------------------------
__global__ __launch_bounds__(256) void gemm_ln_res_kernel(
    const float* __restrict__ ax_A, const float* __restrict__ ax_B,
    const unsigned short* __restrict__ wp,
    const float* __restrict__ b, const float* __restrict__ g,
    const float* __restrict__ be,
    float* __restrict__ out_A, float* __restrict__ out_B)
{
  const float* __restrict__ ax = blockIdx.y ? ax_B : ax_A;
  float* __restrict__ out = blockIdx.y ? out_B : out_A;

  __shared__ __align__(16) unsigned short sA[64*40];    // 5 KB
  __shared__ __align__(16) unsigned short sB[512*40];   // 40 KB
  __shared__ float sb[512], sg[512], sbe[512];          // 6 KB

  const int tid  = threadIdx.x;
  const int wv   = tid >> 6;
  const int lane = tid & 63;
  const int l15  = lane & 15;
  const int quad = lane >> 4;
  const int rbase = blockIdx.x * 64;

  sb[tid]      = b[tid];    sb[tid+256]  = b[tid+256];
  sg[tid]      = g[tid];    sg[tid+256]  = g[tid+256];
  sbe[tid]     = be[tid];   sbe[tid+256] = be[tid+256];

  const f32x4 zero4 = splat4(0.f);
  f32x4 acc[32];
  #pragma unroll
  for (int ct = 0; ct < 32; ++ct) acc[ct] = zero4;

  const int arow = tid >> 2, apart = tid & 3;
  int rres = rbase + arow; if (rres >= R_RES) rres = R_RES - 1;
  const float* abase = ax + (size_t)rres*8*512 + apart*8;

  for (int kc = 0; kc < 16; ++kc) {
    __syncthreads();
    {
      const float* ap = abase + kc*32;
      float4 m0 = *(const float4*)(ap);
      float4 m1 = *(const float4*)(ap + 4);
      #pragma unroll
      for (int a = 1; a < 8; ++a) {
        float4 v0 = *(const float4*)(ap + (size_t)a*512);
        float4 v1 = *(const float4*)(ap + (size_t)a*512 + 4);
        m0.x = fmaxf(m0.x, v0.x); m0.y = fmaxf(m0.y, v0.y);
        m0.z = fmaxf(m0.z, v0.z); m0.w = fmaxf(m0.w, v0.w);
        m1.x = fmaxf(m1.x, v1.x); m1.y = fmaxf(m1.y, v1.y);
        m1.z = fmaxf(m1.z, v1.z); m1.w = fmaxf(m1.w, v1.w);
      }
      ushort4 o0, o1;
      o0.x = f2bf(m0.x); o0.y = f2bf(m0.y); o0.z = f2bf(m0.z); o0.w = f2bf(m0.w);
      o1.x = f2bf(m1.x); o1.y = f2bf(m1.y); o1.z = f2bf(m1.z); o1.w = f2bf(m1.w);
      *(ushort4*)&sA[arow*40 + apart*8]     = o0;
      *(ushort4*)&sA[arow*40 + apart*8 + 4] = o1;
    }
    {
      const float4* src = (const float4*)(wp + (size_t)kc*512*32);
      #pragma unroll
      for (int i = 0; i < 8; ++i) {
        int fi = tid + i*256;
        int n = fi >> 2, part = fi & 3;
        *(float4*)&sB[n*40 + part*8] = src[fi];
      }
    }
    __syncthreads();
    short8 af = *(short8*)&sA[(wv*16 + l15)*40 + quad*8];
    #pragma unroll
    for (int ct = 0; ct < 32; ++ct) {
      short8 bf = *(short8*)&sB[(ct*16 + l15)*40 + quad*8];
      acc[ct] = __builtin_amdgcn_mfma_f32_16x16x32_bf16(af, bf, acc[ct], 0, 0, 0);
    }
  }

  f32x4 p = zero4, q = zero4;
  #pragma unroll
  for (int ct = 0; ct < 32; ++ct) {
    f32x4 t = __builtin_elementwise_max(acc[ct] + splat4(sb[ct*16 + l15]), zero4);
    acc[ct] = t;
    p += t;
    q += t * t;
  }
  #pragma unroll
  for (int i = 0; i < 4; ++i) {
    p[i] = dpp16sum(p[i]);
    q[i] = dpp16sum(q[i]);
  }
  f32x4 mu4  = p * splat4(1.f/512.f);
  f32x4 var4 = __builtin_elementwise_max(q * splat4(1.f/512.f) - mu4*mu4, zero4);
  f32x4 uu, vv;
  #pragma unroll
  for (int i = 0; i < 4; ++i) {
    float inv = rsqrtf(var4[i] + LN_EPS);
    uu[i] = inv; vv[i] = -mu4[i]*inv;
  }
  const int row0 = rbase + wv*16 + quad*4;
  #pragma unroll
  for (int ct = 0; ct < 32; ++ct) {
    int gcol = ct*16 + l15;
    f32x4 v = acc[ct]*uu + vv;
    v = splat4(sg[gcol])*v + splat4(sbe[gcol]);
    #pragma unroll
    for (int i = 0; i < 4; ++i) {
      int grow = row0 + i;
      if (grow < R_RES)
        out[(size_t)grow*512 + gcol] = v[i];
    }
  }
}

// ---------------------------------------------------------------------------
// K5: out[p] = sigmoid((resx_A[src[p]] - resx_B[tgt[p]]) . lin_w + b)
// 8 lanes per pair (128 blocks).
// ---------------------------------------------------------------------------
__global__ __launch_bounds__(256) void final_kernel(
    const float* __restrict__ resx_A, const float* __restrict__ resx_B,
    const int* __restrict__ src_idx, const int* __restrict__ tgt_idx,
    const float* __restrict__ lin_w, const float* __restrict__ lin_b,
    float* __restrict__ outp)
{
  int idx = blockIdx.x*256 + threadIdx.x;
  int p  = idx >> 3;
  int l8 = idx & 7;
  if (p >= P_PAIRS) return;
  const float4* xa = (const float4*)(resx_A + (size_t)src_idx[p]*512) + l8;
  const float4* xb = (const float4*)(resx_B + (size_t)tgt_idx[p]*512) + l8;
  const float4* wv = (const float4*)lin_w + l8;
  float acc = 0.f;
  #pragma unroll
  for (int i = 0; i < 16; ++i) {
    float4 a = xa[i*8], b = xb[i*8], w = wv[i*8];
    acc += (a.x-b.x)*w.x + (a.y-b.y)*w.y + (a.z-b.z)*w.z + (a.w-b.w)*w.w;
  }
  acc += __shfl_xor(acc, 1, 64);
  acc += __shfl_xor(acc, 2, 64);
  acc += __shfl_xor(acc, 4, 64);
  if (l8 == 0) {
    acc += lin_b[0];
    outp[p] = 1.f/(1.f + expf(-acc));
  }
}

extern "C" void kernel_launch(void* const* d_in, const int* in_sizes, int n_in,
                              void* d_out, int out_size, void* d_ws, size_t ws_size,
                              hipStream_t stream)
{
  const float* pos_A   = (const float*)d_in[0];
  const float* nrm_A   = (const float*)d_in[1];
  const float* pos_B   = (const float*)d_in[2];
  const float* nrm_B   = (const float*)d_in[3];
  const int*   edges_A = (const int*)d_in[4];
  const int*   edges_B = (const int*)d_in[5];
  const int*   src_idx = (const int*)d_in[8];
  const int*   tgt_idx = (const int*)d_in[9];
  const float* conv_w1  = (const float*)d_in[11];
  const float* conv_b1  = (const float*)d_in[12];
  const float* conv_g1  = (const float*)d_in[13];
  const float* conv_be1 = (const float*)d_in[14];
  const float* conv_w2  = (const float*)d_in[15];
  const float* conv_b2  = (const float*)d_in[16];
  const float* conv_g2  = (const float*)d_in[17];
  const float* conv_be2 = (const float*)d_in[18];
  const float* atom_w   = (const float*)d_in[19];
  const float* atom_b   = (const float*)d_in[20];
  const float* atom_g   = (const float*)d_in[21];
  const float* atom_be  = (const float*)d_in[22];
  const float* res_w    = (const float*)d_in[23];
  const float* res_b    = (const float*)d_in[24];
  const float* res_g    = (const float*)d_in[25];
  const float* res_be   = (const float*)d_in[26];
  const float* lin1_w   = (const float*)d_in[27];
  const float* lin1_b   = (const float*)d_in[28];

  unsigned short* feats_A = (unsigned short*)d_ws;                 // 12000*384 bf16
  unsigned short* feats_B = feats_A + (size_t)N_ATOMS*384;
  float* atomx_A = (float*)(feats_B + (size_t)N_ATOMS*384);        // 12000*512 f32
  float* atomx_B = atomx_A + (size_t)N_ATOMS*512;
  float* resx_A  = atomx_B + (size_t)N_ATOMS*512;                  // 1500*512 f32
  float* resx_B  = resx_A + (size_t)R_RES*512;
  unsigned short* wpA = (unsigned short*)(resx_B + (size_t)R_RES*512); // 12*512*32 bf16
  unsigned short* wpB = wpA + (size_t)384*512;                         // 16*512*32 bf16

  wpack_kernel<<<(384*512)/256, 256, 0, stream>>>(atom_w, wpA, 384);
  wpack_kernel<<<(512*512)/256, 256, 0, stream>>>(res_w, wpB, 512);

  dim3 gG(N_ATOMS/32, 3, 2);
  edge_fused_kernel<<<gG, 256, 0, stream>>>(pos_A, nrm_A, pos_B, nrm_B,
      edges_A, edges_B,
      conv_w1, conv_b1, conv_g1, conv_be1,
      conv_w2, conv_b2, conv_g2, conv_be2,
      feats_A, feats_B);

  dim3 gAtom((N_ATOMS + 63)/64, 2);
  gemm_ln_kernel<<<gAtom, 256, 0, stream>>>(feats_A, feats_B, wpA,
      atom_b, atom_g, atom_be, atomx_A, atomx_B, N_ATOMS, 384);

  dim3 gRes((R_RES + 63)/64, 2);
  gemm_ln_res_kernel<<<gRes, 256, 0, stream>>>(atomx_A, atomx_B, wpB,
      res_b, res_g, res_be, resx_A, resx_B);

  final_kernel<<<(P_PAIRS*8 + 255)/256, 256, 0, stream>>>(resx_A, resx_B,
      src_idx, tgt_idx, lin1_w, lin1_b, (float*)d_out);
}

// Round 14
// 319.212 us; speedup vs baseline: 1.1842x; 1.0151x over previous
//
#include <hip/hip_runtime.h>
#include <hip/hip_bf16.h>
#include <math.h>

#define N_ATOMS 12000
#define K_NB 32
#define E_EDGES (N_ATOMS*K_NB)   // 384000
#define R_RES 1500
#define P_PAIRS 4096
#define LN_EPS 1e-5f

typedef __attribute__((ext_vector_type(8))) short short8;
typedef __attribute__((ext_vector_type(4))) float f32x4;
typedef __attribute__((ext_vector_type(4))) unsigned int u32x4;

__device__ __forceinline__ f32x4 splat4(float v){ f32x4 r = {v,v,v,v}; return r; }

__device__ __forceinline__ unsigned short f2bf(float f){
  unsigned u = __builtin_bit_cast(unsigned, f);
  u += 0x7FFF + ((u >> 16) & 1);   // RNE
  return (unsigned short)(u >> 16);
}

// async global->LDS, 16B per lane; LDS dest = wave-uniform base + lane*16.
__device__ __forceinline__ void load_lds_16B(const void* gsrc, void* lds_dst){
  __builtin_amdgcn_global_load_lds(
      (const __attribute__((address_space(1))) unsigned int*)gsrc,
      (__attribute__((address_space(3))) unsigned int*)lds_dst, 16, 0, 0);
}

// 16-lane sum-to-all on the VALU pipe via DPP (no DS ops).
template<int CTRL>
__device__ __forceinline__ float dpp_add(float v){
  int x = __builtin_amdgcn_mov_dpp(__builtin_bit_cast(int, v), CTRL, 0xf, 0xf, true);
  return v + __builtin_bit_cast(float, x);
}
__device__ __forceinline__ float dpp16sum(float v){
  v = dpp_add<0xB1>(v);    // quad_perm [1,0,3,2]  : xor 1
  v = dpp_add<0x4E>(v);    // quad_perm [2,3,0,1]  : xor 2
  v = dpp_add<0x141>(v);   // row_half_mirror      : xor 4
  v = dpp_add<0x140>(v);   // row_mirror           : xor 8
  return v;
}

// atan2 for y >= 0 (y = |cross| here), abs err ~1e-5 rad.
__device__ __forceinline__ float fast_atan2(float y, float x){
  float ax = fabsf(x);
  float mn = fminf(ax, y);
  float mx = fmaxf(fmaxf(ax, y), 1e-30f);
  float r  = __builtin_amdgcn_rcpf(mx);
  r = r * (2.0f - mx * r);          // Newton: ~1e-7 rel
  float a = mn * r;                 // in [0,1]
  float s = a * a;
  float p = -0.0117212f;
  p = fmaf(p, s,  0.05265332f);
  p = fmaf(p, s, -0.11643287f);
  p = fmaf(p, s,  0.19354346f);
  p = fmaf(p, s, -0.33262347f);
  p = fmaf(p, s,  0.99997726f);
  p = p * a;
  p = (y > ax) ? (1.57079632679f - p) : p;
  p = (x < 0.f) ? (3.14159265359f - p) : p;
  return p;
}

__device__ __forceinline__ float angle3(float ax,float ay,float az,
                                        float bx,float by,float bz){
  float cx = ay*bz - az*by;
  float cy = az*bx - ax*bz;
  float cz = ax*by - ay*bx;
  float cn = sqrtf(cx*cx + cy*cy + cz*cz);
  float dt = ax*bx + ay*by + az*bz;
  return fast_atan2(cn, dt);
}

// ---------------------------------------------------------------------------
// K0: pack f32 weights [K][512] -> bf16 swizzled chunks. Chunk kc holds 2048
// 16B granules; granule g = n*4 + (quad ^ ((n>>2)&3)) carries
// B[k=kc*32+quad*8 .. +7][n]. XOR swizzle keeps ds_read_b128 fragment reads
// 2-way-bank-aliased (free) while staging is lane-contiguous for
// global_load_lds (wave-uniform base + lane*16 — padding forbidden, m104).
// ---------------------------------------------------------------------------
__global__ __launch_bounds__(256) void wpack_kernel(
    const float* __restrict__ w, unsigned short* __restrict__ wp, int Kdim)
{
  int idx = blockIdx.x*256 + threadIdx.x;
  if (idx >= Kdim*512) return;
  int k = idx >> 9, n = idx & 511;
  int kc = k >> 5, kin = k & 31;
  int quad = kin >> 3, j = kin & 7;
  int g = n*4 + (quad ^ ((n>>2)&3));
  wp[(size_t)kc*16384 + g*8 + j] = f2bf(w[idx]);
}

// ---------------------------------------------------------------------------
// K1 (wave-fused edge stage): UNCHANGED from R13 (proven 124.8us).
// grid: (N/32, 3, 2), block 256 (4 waves).
// ---------------------------------------------------------------------------
__global__ __launch_bounds__(256) void edge_fused_kernel(
    const float* __restrict__ pos_A, const float* __restrict__ nrm_A,
    const float* __restrict__ pos_B, const float* __restrict__ nrm_B,
    const int* __restrict__ edges_A, const int* __restrict__ edges_B,
    const float* __restrict__ w1, const float* __restrict__ b1,
    const float* __restrict__ g1, const float* __restrict__ be1,
    const float* __restrict__ w2, const float* __restrict__ b2,
    const float* __restrict__ g2, const float* __restrict__ be2,
    unsigned short* __restrict__ feats_A, unsigned short* __restrict__ feats_B)
{
  const int r = blockIdx.y;
  const int side = blockIdx.z;
  const float* __restrict__ pos = side ? pos_B : pos_A;
  const float* __restrict__ nrm = side ? nrm_B : nrm_A;
  const int* __restrict__ edges = (side ? edges_B : edges_A) + r*(2*E_EDGES);
  unsigned short* __restrict__ feats = side ? feats_B : feats_A;

  const int tid  = threadIdx.x;
  const int wv   = tid >> 6;
  const int lane = tid & 63;
  const int l15  = lane & 15;
  const bool live = (lane < 16);

  const float* __restrict__ w1r  = w1  + r*16;
  const float* __restrict__ b1r  = b1  + r*4;
  const float* __restrict__ g1r  = g1  + r*4;
  const float* __restrict__ be1r = be1 + r*4;
  const float* __restrict__ w2r  = w2  + r*512;   // [4][128]

  short8 bfrag[8];
  float bias[8], gg[8], ee[8];
  #pragma unroll
  for (int ct = 0; ct < 8; ++ct) {
    int n = ct*16 + l15;
    float v0 = w2r[0*128+n], v1 = w2r[1*128+n];
    float v2 = w2r[2*128+n], v3 = w2r[3*128+n];
    short8 bf = {0,0,0,0,0,0,0,0};
    bf[0] = live ? (short)f2bf(v0) : (short)0;
    bf[1] = live ? (short)f2bf(v1) : (short)0;
    bf[2] = live ? (short)f2bf(v2) : (short)0;
    bf[3] = live ? (short)f2bf(v3) : (short)0;
    bfrag[ct] = bf;
    bias[ct] = b2[r*128+n];
    gg[ct]   = g2[r*128+n];
    ee[ct]   = be2[r*128+n];
  }

  const int node0 = blockIdx.x*32 + wv*8;
  const f32x4 zero4 = splat4(0.f);

  for (int win = 0; win < 4; ++win) {
    const int e = (node0 + win*2)*K_NB + lane;
    const int src = edges[e];
    const int dst = e >> 5;

    float psx = pos[src*3+0], psy = pos[src*3+1], psz = pos[src*3+2];
    float pdx = pos[dst*3+0], pdy = pos[dst*3+1], pdz = pos[dst*3+2];
    float dx = psx-pdx, dy = psy-pdy, dz = psz-pdz;
    float nix = nrm[dst*3+0], niy = nrm[dst*3+1], niz = nrm[dst*3+2];
    float njx = nrm[src*3+0], njy = nrm[src*3+1], njz = nrm[src*3+2];

    float f0 = sqrtf(dx*dx + dy*dy + dz*dz);
    float f1 = angle3(nix,niy,niz, dx,dy,dz);
    float f2 = angle3(njx,njy,njz, dx,dy,dz);
    float f3 = angle3(nix,niy,niz, njx,njy,njz);

    float h[4]; float s1 = 0.f;
    #pragma unroll
    for (int j = 0; j < 4; ++j) {
      float t = b1r[j] + f0*w1r[j] + f1*w1r[4+j] + f2*w1r[8+j] + f3*w1r[12+j];
      t = fmaxf(t, 0.f);
      h[j] = t; s1 += t;
    }
    float mu1 = s1*0.25f;
    float v1 = 0.f;
    #pragma unroll
    for (int j = 0; j < 4; ++j) { float d = h[j]-mu1; v1 += d*d; }
    float inv1 = rsqrtf(v1*0.25f + LN_EPS);
    float a0 = g1r[0]*(h[0]-mu1)*inv1 + be1r[0];
    float a1 = g1r[1]*(h[1]-mu1)*inv1 + be1r[1];
    float a2 = g1r[2]*(h[2]-mu1)*inv1 + be1r[2];
    float a3 = g1r[3]*(h[3]-mu1)*inv1 + be1r[3];

    unsigned alo = (unsigned)f2bf(a0) | ((unsigned)f2bf(a1) << 16);
    unsigned ahi = (unsigned)f2bf(a2) | ((unsigned)f2bf(a3) << 16);

    #pragma unroll
    for (int nd2 = 0; nd2 < 2; ++nd2) {
      float nodemax[8];
      #pragma unroll
      for (int ct = 0; ct < 8; ++ct) nodemax[ct] = -3.4e38f;

      #pragma unroll
      for (int rt = 0; rt < 2; ++rt) {
        const int srcl = nd2*32 + rt*16 + l15;
        unsigned palo = __shfl(alo, srcl, 64);
        unsigned pahi = __shfl(ahi, srcl, 64);
        palo = live ? palo : 0u;
        pahi = live ? pahi : 0u;
        u32x4 pk = {palo, pahi, 0u, 0u};
        short8 af = __builtin_bit_cast(short8, pk);

        f32x4 acc[8];
        #pragma unroll
        for (int ct = 0; ct < 8; ++ct)
          acc[ct] = __builtin_amdgcn_mfma_f32_16x16x32_bf16(af, bfrag[ct], zero4, 0, 0, 0);

        float p[4] = {0,0,0,0}, q[4] = {0,0,0,0};
        #pragma unroll
        for (int ct = 0; ct < 8; ++ct) {
          #pragma unroll
          for (int i = 0; i < 4; ++i) {
            float t = fmaxf(acc[ct][i] + bias[ct], 0.f);
            acc[ct][i] = t; p[i] += t; q[i] = fmaf(t, t, q[i]);
          }
        }
        #pragma unroll
        for (int i = 0; i < 4; ++i) {
          p[i] = dpp16sum(p[i]);
          q[i] = dpp16sum(q[i]);
        }
        float uu[4], vv[4];
        #pragma unroll
        for (int i = 0; i < 4; ++i) {
          float mu  = p[i]*(1.f/128.f);
          float var = fmaxf(q[i]*(1.f/128.f) - mu*mu, 0.f);
          float inv = rsqrtf(var + LN_EPS);
          uu[i] = inv; vv[i] = -mu*inv;
        }
        #pragma unroll
        for (int ct = 0; ct < 8; ++ct) {
          float vm = -3.4e38f;
          #pragma unroll
          for (int i = 0; i < 4; ++i) {
            float val = gg[ct]*fmaf(acc[ct][i], uu[i], vv[i]) + ee[ct];
            vm = fmaxf(vm, val);
          }
          nodemax[ct] = fmaxf(nodemax[ct], vm);
        }
      }

      #pragma unroll
      for (int ct = 0; ct < 8; ++ct) {
        float vm = nodemax[ct];
        vm = fmaxf(vm, __shfl_xor(vm, 16, 64));
        vm = fmaxf(vm, __shfl_xor(vm, 32, 64));
        nodemax[ct] = vm;
      }

      if (live) {
        const int gnode = node0 + win*2 + nd2;
        #pragma unroll
        for (int ct = 0; ct < 8; ++ct)
          feats[(size_t)gnode*384 + r*128 + ct*16 + l15] = f2bf(nodemax[ct]);
      }
    }
  }
}

// ---------------------------------------------------------------------------
// K3: atom layer GEMM+LN. B staged via global_load_lds (16B, swizzled wp —
// no VGPR round-trip, no per-chunk vmcnt stall before ds_write; drain happens
// at the barrier). Fragment read: granule n*4 + (quad ^ ((n>>2)&3)).
// grid: (ceil(nrows/64), 2), block 256.
// ---------------------------------------------------------------------------
__global__ __launch_bounds__(256) void gemm_ln_kernel(
    const unsigned short* __restrict__ x_A, const unsigned short* __restrict__ x_B,
    const unsigned short* __restrict__ wp,
    const float* __restrict__ b, const float* __restrict__ g,
    const float* __restrict__ be,
    float* __restrict__ out_A, float* __restrict__ out_B,
    int nrows, int Kdim)
{
  const unsigned short* __restrict__ x = blockIdx.y ? x_B : x_A;
  float* __restrict__ out = blockIdx.y ? out_B : out_A;

  __shared__ __align__(16) unsigned short sA[64*40];    // 5 KB (padded, VGPR path)
  __shared__ __align__(16) unsigned short sB[512*32];   // 32 KB (swizzled, async path)
  __shared__ float sb[512], sg[512], sbe[512];          // 6 KB

  const int tid  = threadIdx.x;
  const int wv   = tid >> 6;
  const int lane = tid & 63;
  const int l15  = lane & 15;
  const int quad = lane >> 4;
  const int rbase = blockIdx.x * 64;

  sb[tid]      = b[tid];    sb[tid+256]  = b[tid+256];
  sg[tid]      = g[tid];    sg[tid+256]  = g[tid+256];
  sbe[tid]     = be[tid];   sbe[tid+256] = be[tid+256];

  const f32x4 zero4 = splat4(0.f);
  f32x4 acc[32];
  #pragma unroll
  for (int ct = 0; ct < 32; ++ct) acc[ct] = zero4;

  const int nchunk = Kdim >> 5;
  const int arow = tid >> 2, apart = tid & 3;
  int agr = rbase + arow; if (agr >= nrows) agr = nrows - 1;
  const unsigned short* aptr = x + (size_t)agr*Kdim + apart*8;

  for (int kc = 0; kc < nchunk; ++kc) {
    __syncthreads();
    // A chunk (small): VGPR path into padded sA
    *(float4*)&sA[arow*40 + apart*8] = *(const float4*)(aptr + kc*32);
    // B chunk (32KB): async direct-to-LDS, 8 x 1KB per wave
    {
      const unsigned short* wsrc = wp + (size_t)kc*16384;
      #pragma unroll
      for (int i = 0; i < 8; ++i) {
        int g0 = (wv*8 + i)*64;                          // wave-uniform granule base
        load_lds_16B(wsrc + (size_t)(g0 + lane)*8, &sB[g0*8]);
      }
    }
    __syncthreads();
    short8 af = *(short8*)&sA[(wv*16 + l15)*40 + quad*8];
    #pragma unroll
    for (int ct = 0; ct < 32; ++ct) {
      int n = ct*16 + l15;
      int gidx = n*4 + (quad ^ ((n>>2)&3));
      short8 bf = *(short8*)&sB[gidx*8];
      acc[ct] = __builtin_amdgcn_mfma_f32_16x16x32_bf16(af, bf, acc[ct], 0, 0, 0);
    }
  }

  f32x4 p = zero4, q = zero4;
  #pragma unroll
  for (int ct = 0; ct < 32; ++ct) {
    f32x4 t = __builtin_elementwise_max(acc[ct] + splat4(sb[ct*16 + l15]), zero4);
    acc[ct] = t;
    p += t;
    q += t * t;
  }
  #pragma unroll
  for (int i = 0; i < 4; ++i) {
    p[i] = dpp16sum(p[i]);
    q[i] = dpp16sum(q[i]);
  }
  f32x4 mu4  = p * splat4(1.f/512.f);
  f32x4 var4 = __builtin_elementwise_max(q * splat4(1.f/512.f) - mu4*mu4, zero4);
  f32x4 uu, vv;
  #pragma unroll
  for (int i = 0; i < 4; ++i) {
    float inv = rsqrtf(var4[i] + LN_EPS);
    uu[i] = inv; vv[i] = -mu4[i]*inv;
  }
  const int row0 = rbase + wv*16 + quad*4;
  #pragma unroll
  for (int ct = 0; ct < 32; ++ct) {
    int gcol = ct*16 + l15;
    f32x4 v = acc[ct]*uu + vv;
    v = splat4(sg[gcol])*v + splat4(sbe[gcol]);
    #pragma unroll
    for (int i = 0; i < 4; ++i) {
      int grow = row0 + i;
      if (grow < nrows)
        out[(size_t)grow*512 + gcol] = v[i];
    }
  }
}

// ---------------------------------------------------------------------------
// K4: res layer, fused residue-max A-staging + async B staging (as K3).
// grid: (ceil(R/64), 2), block 256.
// ---------------------------------------------------------------------------
__global__ __launch_bounds__(256) void gemm_ln_res_kernel(
    const float* __restrict__ ax_A, const float* __restrict__ ax_B,
    const unsigned short* __restrict__ wp,
    const float* __restrict__ b, const float* __restrict__ g,
    const float* __restrict__ be,
    float* __restrict__ out_A, float* __restrict__ out_B)
{
  const float* __restrict__ ax = blockIdx.y ? ax_B : ax_A;
  float* __restrict__ out = blockIdx.y ? out_B : out_A;

  __shared__ __align__(16) unsigned short sA[64*40];    // 5 KB
  __shared__ __align__(16) unsigned short sB[512*32];   // 32 KB
  __shared__ float sb[512], sg[512], sbe[512];          // 6 KB

  const int tid  = threadIdx.x;
  const int wv   = tid >> 6;
  const int lane = tid & 63;
  const int l15  = lane & 15;
  const int quad = lane >> 4;
  const int rbase = blockIdx.x * 64;

  sb[tid]      = b[tid];    sb[tid+256]  = b[tid+256];
  sg[tid]      = g[tid];    sg[tid+256]  = g[tid+256];
  sbe[tid]     = be[tid];   sbe[tid+256] = be[tid+256];

  const f32x4 zero4 = splat4(0.f);
  f32x4 acc[32];
  #pragma unroll
  for (int ct = 0; ct < 32; ++ct) acc[ct] = zero4;

  const int arow = tid >> 2, apart = tid & 3;
  int rres = rbase + arow; if (rres >= R_RES) rres = R_RES - 1;
  const float* abase = ax + (size_t)rres*8*512 + apart*8;

  for (int kc = 0; kc < 16; ++kc) {
    __syncthreads();
    // fused resmax A-staging (VGPR path, padded sA)
    {
      const float* ap = abase + kc*32;
      float4 m0 = *(const float4*)(ap);
      float4 m1 = *(const float4*)(ap + 4);
      #pragma unroll
      for (int a = 1; a < 8; ++a) {
        float4 v0 = *(const float4*)(ap + (size_t)a*512);
        float4 v1 = *(const float4*)(ap + (size_t)a*512 + 4);
        m0.x = fmaxf(m0.x, v0.x); m0.y = fmaxf(m0.y, v0.y);
        m0.z = fmaxf(m0.z, v0.z); m0.w = fmaxf(m0.w, v0.w);
        m1.x = fmaxf(m1.x, v1.x); m1.y = fmaxf(m1.y, v1.y);
        m1.z = fmaxf(m1.z, v1.z); m1.w = fmaxf(m1.w, v1.w);
      }
      ushort4 o0, o1;
      o0.x = f2bf(m0.x); o0.y = f2bf(m0.y); o0.z = f2bf(m0.z); o0.w = f2bf(m0.w);
      o1.x = f2bf(m1.x); o1.y = f2bf(m1.y); o1.z = f2bf(m1.z); o1.w = f2bf(m1.w);
      *(ushort4*)&sA[arow*40 + apart*8]     = o0;
      *(ushort4*)&sA[arow*40 + apart*8 + 4] = o1;
    }
    // async B staging
    {
      const unsigned short* wsrc = wp + (size_t)kc*16384;
      #pragma unroll
      for (int i = 0; i < 8; ++i) {
        int g0 = (wv*8 + i)*64;
        load_lds_16B(wsrc + (size_t)(g0 + lane)*8, &sB[g0*8]);
      }
    }
    __syncthreads();
    short8 af = *(short8*)&sA[(wv*16 + l15)*40 + quad*8];
    #pragma unroll
    for (int ct = 0; ct < 32; ++ct) {
      int n = ct*16 + l15;
      int gidx = n*4 + (quad ^ ((n>>2)&3));
      short8 bf = *(short8*)&sB[gidx*8];
      acc[ct] = __builtin_amdgcn_mfma_f32_16x16x32_bf16(af, bf, acc[ct], 0, 0, 0);
    }
  }

  f32x4 p = zero4, q = zero4;
  #pragma unroll
  for (int ct = 0; ct < 32; ++ct) {
    f32x4 t = __builtin_elementwise_max(acc[ct] + splat4(sb[ct*16 + l15]), zero4);
    acc[ct] = t;
    p += t;
    q += t * t;
  }
  #pragma unroll
  for (int i = 0; i < 4; ++i) {
    p[i] = dpp16sum(p[i]);
    q[i] = dpp16sum(q[i]);
  }
  f32x4 mu4  = p * splat4(1.f/512.f);
  f32x4 var4 = __builtin_elementwise_max(q * splat4(1.f/512.f) - mu4*mu4, zero4);
  f32x4 uu, vv;
  #pragma unroll
  for (int i = 0; i < 4; ++i) {
    float inv = rsqrtf(var4[i] + LN_EPS);
    uu[i] = inv; vv[i] = -mu4[i]*inv;
  }
  const int row0 = rbase + wv*16 + quad*4;
  #pragma unroll
  for (int ct = 0; ct < 32; ++ct) {
    int gcol = ct*16 + l15;
    f32x4 v = acc[ct]*uu + vv;
    v = splat4(sg[gcol])*v + splat4(sbe[gcol]);
    #pragma unroll
    for (int i = 0; i < 4; ++i) {
      int grow = row0 + i;
      if (grow < R_RES)
        out[(size_t)grow*512 + gcol] = v[i];
    }
  }
}

// ---------------------------------------------------------------------------
// K5: out[p] = sigmoid((resx_A[src[p]] - resx_B[tgt[p]]) . lin_w + b)
// 8 lanes per pair (128 blocks).
// ---------------------------------------------------------------------------
__global__ __launch_bounds__(256) void final_kernel(
    const float* __restrict__ resx_A, const float* __restrict__ resx_B,
    const int* __restrict__ src_idx, const int* __restrict__ tgt_idx,
    const float* __restrict__ lin_w, const float* __restrict__ lin_b,
    float* __restrict__ outp)
{
  int idx = blockIdx.x*256 + threadIdx.x;
  int p  = idx >> 3;
  int l8 = idx & 7;
  if (p >= P_PAIRS) return;
  const float4* xa = (const float4*)(resx_A + (size_t)src_idx[p]*512) + l8;
  const float4* xb = (const float4*)(resx_B + (size_t)tgt_idx[p]*512) + l8;
  const float4* wv = (const float4*)lin_w + l8;
  float acc = 0.f;
  #pragma unroll
  for (int i = 0; i < 16; ++i) {
    float4 a = xa[i*8], b = xb[i*8], w = wv[i*8];
    acc += (a.x-b.x)*w.x + (a.y-b.y)*w.y + (a.z-b.z)*w.z + (a.w-b.w)*w.w;
  }
  acc += __shfl_xor(acc, 1, 64);
  acc += __shfl_xor(acc, 2, 64);
  acc += __shfl_xor(acc, 4, 64);
  if (l8 == 0) {
    acc += lin_b[0];
    outp[p] = 1.f/(1.f + expf(-acc));
  }
}

extern "C" void kernel_launch(void* const* d_in, const int* in_sizes, int n_in,
                              void* d_out, int out_size, void* d_ws, size_t ws_size,
                              hipStream_t stream)
{
  const float* pos_A   = (const float*)d_in[0];
  const float* nrm_A   = (const float*)d_in[1];
  const float* pos_B   = (const float*)d_in[2];
  const float* nrm_B   = (const float*)d_in[3];
  const int*   edges_A = (const int*)d_in[4];
  const int*   edges_B = (const int*)d_in[5];
  const int*   src_idx = (const int*)d_in[8];
  const int*   tgt_idx = (const int*)d_in[9];
  const float* conv_w1  = (const float*)d_in[11];
  const float* conv_b1  = (const float*)d_in[12];
  const float* conv_g1  = (const float*)d_in[13];
  const float* conv_be1 = (const float*)d_in[14];
  const float* conv_w2  = (const float*)d_in[15];
  const float* conv_b2  = (const float*)d_in[16];
  const float* conv_g2  = (const float*)d_in[17];
  const float* conv_be2 = (const float*)d_in[18];
  const float* atom_w   = (const float*)d_in[19];
  const float* atom_b   = (const float*)d_in[20];
  const float* atom_g   = (const float*)d_in[21];
  const float* atom_be  = (const float*)d_in[22];
  const float* res_w    = (const float*)d_in[23];
  const float* res_b    = (const float*)d_in[24];
  const float* res_g    = (const float*)d_in[25];
  const float* res_be   = (const float*)d_in[26];
  const float* lin1_w   = (const float*)d_in[27];
  const float* lin1_b   = (const float*)d_in[28];

  unsigned short* feats_A = (unsigned short*)d_ws;                 // 12000*384 bf16
  unsigned short* feats_B = feats_A + (size_t)N_ATOMS*384;
  float* atomx_A = (float*)(feats_B + (size_t)N_ATOMS*384);        // 12000*512 f32
  float* atomx_B = atomx_A + (size_t)N_ATOMS*512;
  float* resx_A  = atomx_B + (size_t)N_ATOMS*512;                  // 1500*512 f32
  float* resx_B  = resx_A + (size_t)R_RES*512;
  unsigned short* wpA = (unsigned short*)(resx_B + (size_t)R_RES*512); // 12*16384 bf16
  unsigned short* wpB = wpA + (size_t)384*512;                         // 16*16384 bf16

  wpack_kernel<<<(384*512)/256, 256, 0, stream>>>(atom_w, wpA, 384);
  wpack_kernel<<<(512*512)/256, 256, 0, stream>>>(res_w, wpB, 512);

  dim3 gG(N_ATOMS/32, 3, 2);
  edge_fused_kernel<<<gG, 256, 0, stream>>>(pos_A, nrm_A, pos_B, nrm_B,
      edges_A, edges_B,
      conv_w1, conv_b1, conv_g1, conv_be1,
      conv_w2, conv_b2, conv_g2, conv_be2,
      feats_A, feats_B);

  dim3 gAtom((N_ATOMS + 63)/64, 2);
  gemm_ln_kernel<<<gAtom, 256, 0, stream>>>(feats_A, feats_B, wpA,
      atom_b, atom_g, atom_be, atomx_A, atomx_B, N_ATOMS, 384);

  dim3 gRes((R_RES + 63)/64, 2);
  gemm_ln_res_kernel<<<gRes, 256, 0, stream>>>(atomx_A, atomx_B, wpB,
      res_b, res_g, res_be, resx_A, resx_B);

  final_kernel<<<(P_PAIRS*8 + 255)/256, 256, 0, stream>>>(resx_A, resx_B,
      src_idx, tgt_idx, lin1_w, lin1_b, (float*)d_out);
}

// Round 15
// 304.618 us; speedup vs baseline: 1.2409x; 1.0479x over previous
//
#include <hip/hip_runtime.h>
#include <hip/hip_bf16.h>
#include <math.h>

#define N_ATOMS 12000
#define K_NB 32
#define E_EDGES (N_ATOMS*K_NB)   // 384000
#define R_RES 1500
#define P_PAIRS 4096
#define LN_EPS 1e-5f

typedef __attribute__((ext_vector_type(8))) short short8;
typedef __attribute__((ext_vector_type(4))) float f32x4;
typedef __attribute__((ext_vector_type(4))) unsigned int u32x4;

__device__ __forceinline__ f32x4 splat4(float v){ f32x4 r = {v,v,v,v}; return r; }

__device__ __forceinline__ unsigned short f2bf(float f){
  unsigned u = __builtin_bit_cast(unsigned, f);
  u += 0x7FFF + ((u >> 16) & 1);   // RNE
  return (unsigned short)(u >> 16);
}

// raw-instruction transcendentals (skip libm's precise-fixup sequences;
// ~1ulp, fine ahead of bf16 rounding)
__device__ __forceinline__ float fast_rsqrt(float x){ return __builtin_amdgcn_rsqf(x); }
__device__ __forceinline__ float fast_sqrt (float x){ return __builtin_amdgcn_sqrtf(x); }

// async global->LDS, 16B per lane; LDS dest = wave-uniform base + lane*16.
__device__ __forceinline__ void load_lds_16B(const void* gsrc, void* lds_dst){
  __builtin_amdgcn_global_load_lds(
      (const __attribute__((address_space(1))) unsigned int*)gsrc,
      (__attribute__((address_space(3))) unsigned int*)lds_dst, 16, 0, 0);
}

// 16-lane sum-to-all on the VALU pipe via DPP (no DS ops).
template<int CTRL>
__device__ __forceinline__ float dpp_add(float v){
  int x = __builtin_amdgcn_mov_dpp(__builtin_bit_cast(int, v), CTRL, 0xf, 0xf, true);
  return v + __builtin_bit_cast(float, x);
}
__device__ __forceinline__ float dpp16sum(float v){
  v = dpp_add<0xB1>(v);    // quad_perm [1,0,3,2]  : xor 1
  v = dpp_add<0x4E>(v);    // quad_perm [2,3,0,1]  : xor 2
  v = dpp_add<0x141>(v);   // row_half_mirror      : xor 4
  v = dpp_add<0x140>(v);   // row_mirror           : xor 8
  return v;
}

// atan2 for y >= 0 (y = |cross| here), abs err ~1e-5 rad.
__device__ __forceinline__ float fast_atan2(float y, float x){
  float ax = fabsf(x);
  float mn = fminf(ax, y);
  float mx = fmaxf(fmaxf(ax, y), 1e-30f);
  float r  = __builtin_amdgcn_rcpf(mx);
  r = r * (2.0f - mx * r);          // Newton: ~1e-7 rel
  float a = mn * r;                 // in [0,1]
  float s = a * a;
  float p = -0.0117212f;
  p = fmaf(p, s,  0.05265332f);
  p = fmaf(p, s, -0.11643287f);
  p = fmaf(p, s,  0.19354346f);
  p = fmaf(p, s, -0.33262347f);
  p = fmaf(p, s,  0.99997726f);
  p = p * a;
  p = (y > ax) ? (1.57079632679f - p) : p;
  p = (x < 0.f) ? (3.14159265359f - p) : p;
  return p;
}

__device__ __forceinline__ float angle3(float ax,float ay,float az,
                                        float bx,float by,float bz){
  float cx = ay*bz - az*by;
  float cy = az*bx - ax*bz;
  float cz = ax*by - ay*bx;
  float cn = fast_sqrt(cx*cx + cy*cy + cz*cz);
  float dt = ax*bx + ay*by + az*bz;
  return fast_atan2(cn, dt);
}

// ---------------------------------------------------------------------------
// K0: pack f32 weights [K][512] -> bf16 swizzled chunks (granule
// g = n*4 + (quad ^ ((n>>2)&3)); async-staging layout, see R14 notes).
// ---------------------------------------------------------------------------
__global__ __launch_bounds__(256) void wpack_kernel(
    const float* __restrict__ w, unsigned short* __restrict__ wp, int Kdim)
{
  int idx = blockIdx.x*256 + threadIdx.x;
  if (idx >= Kdim*512) return;
  int k = idx >> 9, n = idx & 511;
  int kc = k >> 5, kin = k & 31;
  int quad = kin >> 3, j = kin & 7;
  int g = n*4 + (quad ^ ((n>>2)&3));
  wp[(size_t)kc*16384 + g*8 + j] = f2bf(w[idx]);
}

// ---------------------------------------------------------------------------
// K1 (wave-fused edge stage): R13 structure + instruction diet:
//  - raw v_sqrt/v_rsq (no libm fixups)
//  - A-fragment lane-masking dropped (provably redundant: bfrag already zero
//    for lanes>=16 and j>=4, so those MFMA products vanish regardless of A)
// grid: (N/32, 3, 2), block 256 (4 waves).
// ---------------------------------------------------------------------------
__global__ __launch_bounds__(256) void edge_fused_kernel(
    const float* __restrict__ pos_A, const float* __restrict__ nrm_A,
    const float* __restrict__ pos_B, const float* __restrict__ nrm_B,
    const int* __restrict__ edges_A, const int* __restrict__ edges_B,
    const float* __restrict__ w1, const float* __restrict__ b1,
    const float* __restrict__ g1, const float* __restrict__ be1,
    const float* __restrict__ w2, const float* __restrict__ b2,
    const float* __restrict__ g2, const float* __restrict__ be2,
    unsigned short* __restrict__ feats_A, unsigned short* __restrict__ feats_B)
{
  const int r = blockIdx.y;
  const int side = blockIdx.z;
  const float* __restrict__ pos = side ? pos_B : pos_A;
  const float* __restrict__ nrm = side ? nrm_B : nrm_A;
  const int* __restrict__ edges = (side ? edges_B : edges_A) + r*(2*E_EDGES);
  unsigned short* __restrict__ feats = side ? feats_B : feats_A;

  const int tid  = threadIdx.x;
  const int wv   = tid >> 6;
  const int lane = tid & 63;
  const int l15  = lane & 15;
  const bool live = (lane < 16);

  const float* __restrict__ w1r  = w1  + r*16;
  const float* __restrict__ b1r  = b1  + r*4;
  const float* __restrict__ g1r  = g1  + r*4;
  const float* __restrict__ be1r = be1 + r*4;
  const float* __restrict__ w2r  = w2  + r*512;   // [4][128]

  short8 bfrag[8];
  float bias[8], gg[8], ee[8];
  #pragma unroll
  for (int ct = 0; ct < 8; ++ct) {
    int n = ct*16 + l15;
    float v0 = w2r[0*128+n], v1 = w2r[1*128+n];
    float v2 = w2r[2*128+n], v3 = w2r[3*128+n];
    short8 bf = {0,0,0,0,0,0,0,0};
    bf[0] = live ? (short)f2bf(v0) : (short)0;
    bf[1] = live ? (short)f2bf(v1) : (short)0;
    bf[2] = live ? (short)f2bf(v2) : (short)0;
    bf[3] = live ? (short)f2bf(v3) : (short)0;
    bfrag[ct] = bf;
    bias[ct] = b2[r*128+n];
    gg[ct]   = g2[r*128+n];
    ee[ct]   = be2[r*128+n];
  }

  const int node0 = blockIdx.x*32 + wv*8;
  const f32x4 zero4 = splat4(0.f);

  for (int win = 0; win < 4; ++win) {
    const int e = (node0 + win*2)*K_NB + lane;
    const int src = edges[e];
    const int dst = e >> 5;

    float psx = pos[src*3+0], psy = pos[src*3+1], psz = pos[src*3+2];
    float pdx = pos[dst*3+0], pdy = pos[dst*3+1], pdz = pos[dst*3+2];
    float dx = psx-pdx, dy = psy-pdy, dz = psz-pdz;
    float nix = nrm[dst*3+0], niy = nrm[dst*3+1], niz = nrm[dst*3+2];
    float njx = nrm[src*3+0], njy = nrm[src*3+1], njz = nrm[src*3+2];

    float f0 = fast_sqrt(dx*dx + dy*dy + dz*dz);
    float f1 = angle3(nix,niy,niz, dx,dy,dz);
    float f2 = angle3(njx,njy,njz, dx,dy,dz);
    float f3 = angle3(nix,niy,niz, njx,njy,njz);

    float h[4]; float s1 = 0.f;
    #pragma unroll
    for (int j = 0; j < 4; ++j) {
      float t = b1r[j] + f0*w1r[j] + f1*w1r[4+j] + f2*w1r[8+j] + f3*w1r[12+j];
      t = fmaxf(t, 0.f);
      h[j] = t; s1 += t;
    }
    float mu1 = s1*0.25f;
    float v1 = 0.f;
    #pragma unroll
    for (int j = 0; j < 4; ++j) { float d = h[j]-mu1; v1 += d*d; }
    float inv1 = fast_rsqrt(v1*0.25f + LN_EPS);
    float a0 = g1r[0]*(h[0]-mu1)*inv1 + be1r[0];
    float a1 = g1r[1]*(h[1]-mu1)*inv1 + be1r[1];
    float a2 = g1r[2]*(h[2]-mu1)*inv1 + be1r[2];
    float a3 = g1r[3]*(h[3]-mu1)*inv1 + be1r[3];

    unsigned alo = (unsigned)f2bf(a0) | ((unsigned)f2bf(a1) << 16);
    unsigned ahi = (unsigned)f2bf(a2) | ((unsigned)f2bf(a3) << 16);

    #pragma unroll
    for (int nd2 = 0; nd2 < 2; ++nd2) {
      float nodemax[8];
      #pragma unroll
      for (int ct = 0; ct < 8; ++ct) nodemax[ct] = -3.4e38f;

      #pragma unroll
      for (int rt = 0; rt < 2; ++rt) {
        const int srcl = nd2*32 + rt*16 + l15;
        // no live-masking: B is zero for lanes>=16 / j>=4, products vanish
        unsigned palo = __shfl(alo, srcl, 64);
        unsigned pahi = __shfl(ahi, srcl, 64);
        u32x4 pk = {palo, pahi, 0u, 0u};
        short8 af = __builtin_bit_cast(short8, pk);

        f32x4 acc[8];
        #pragma unroll
        for (int ct = 0; ct < 8; ++ct)
          acc[ct] = __builtin_amdgcn_mfma_f32_16x16x32_bf16(af, bfrag[ct], zero4, 0, 0, 0);

        float p[4] = {0,0,0,0}, q[4] = {0,0,0,0};
        #pragma unroll
        for (int ct = 0; ct < 8; ++ct) {
          #pragma unroll
          for (int i = 0; i < 4; ++i) {
            float t = fmaxf(acc[ct][i] + bias[ct], 0.f);
            acc[ct][i] = t; p[i] += t; q[i] = fmaf(t, t, q[i]);
          }
        }
        #pragma unroll
        for (int i = 0; i < 4; ++i) {
          p[i] = dpp16sum(p[i]);
          q[i] = dpp16sum(q[i]);
        }
        float uu[4], vv[4];
        #pragma unroll
        for (int i = 0; i < 4; ++i) {
          float mu  = p[i]*(1.f/128.f);
          float var = fmaxf(q[i]*(1.f/128.f) - mu*mu, 0.f);
          float inv = fast_rsqrt(var + LN_EPS);
          uu[i] = inv; vv[i] = -mu*inv;
        }
        #pragma unroll
        for (int ct = 0; ct < 8; ++ct) {
          float vm = -3.4e38f;
          #pragma unroll
          for (int i = 0; i < 4; ++i) {
            float val = gg[ct]*fmaf(acc[ct][i], uu[i], vv[i]) + ee[ct];
            vm = fmaxf(vm, val);
          }
          nodemax[ct] = fmaxf(nodemax[ct], vm);
        }
      }

      #pragma unroll
      for (int ct = 0; ct < 8; ++ct) {
        float vm = nodemax[ct];
        vm = fmaxf(vm, __shfl_xor(vm, 16, 64));
        vm = fmaxf(vm, __shfl_xor(vm, 32, 64));
        nodemax[ct] = vm;
      }

      if (live) {
        const int gnode = node0 + win*2 + nd2;
        #pragma unroll
        for (int ct = 0; ct < 8; ++ct)
          feats[(size_t)gnode*384 + r*128 + ct*16 + l15] = f2bf(nodemax[ct]);
      }
    }
  }
}

// ---------------------------------------------------------------------------
// K3: atom layer GEMM+LN, async B staging (R14-proven).
// grid: (ceil(nrows/64), 2), block 256.
// ---------------------------------------------------------------------------
__global__ __launch_bounds__(256) void gemm_ln_kernel(
    const unsigned short* __restrict__ x_A, const unsigned short* __restrict__ x_B,
    const unsigned short* __restrict__ wp,
    const float* __restrict__ b, const float* __restrict__ g,
    const float* __restrict__ be,
    float* __restrict__ out_A, float* __restrict__ out_B,
    int nrows, int Kdim)
{
  const unsigned short* __restrict__ x = blockIdx.y ? x_B : x_A;
  float* __restrict__ out = blockIdx.y ? out_B : out_A;

  __shared__ __align__(16) unsigned short sA[64*40];    // 5 KB (padded, VGPR path)
  __shared__ __align__(16) unsigned short sB[512*32];   // 32 KB (swizzled, async path)
  __shared__ float sb[512], sg[512], sbe[512];          // 6 KB

  const int tid  = threadIdx.x;
  const int wv   = tid >> 6;
  const int lane = tid & 63;
  const int l15  = lane & 15;
  const int quad = lane >> 4;
  const int rbase = blockIdx.x * 64;

  sb[tid]      = b[tid];    sb[tid+256]  = b[tid+256];
  sg[tid]      = g[tid];    sg[tid+256]  = g[tid+256];
  sbe[tid]     = be[tid];   sbe[tid+256] = be[tid+256];

  const f32x4 zero4 = splat4(0.f);
  f32x4 acc[32];
  #pragma unroll
  for (int ct = 0; ct < 32; ++ct) acc[ct] = zero4;

  const int nchunk = Kdim >> 5;
  const int arow = tid >> 2, apart = tid & 3;
  int agr = rbase + arow; if (agr >= nrows) agr = nrows - 1;
  const unsigned short* aptr = x + (size_t)agr*Kdim + apart*8;

  for (int kc = 0; kc < nchunk; ++kc) {
    __syncthreads();
    *(float4*)&sA[arow*40 + apart*8] = *(const float4*)(aptr + kc*32);
    {
      const unsigned short* wsrc = wp + (size_t)kc*16384;
      #pragma unroll
      for (int i = 0; i < 8; ++i) {
        int g0 = (wv*8 + i)*64;
        load_lds_16B(wsrc + (size_t)(g0 + lane)*8, &sB[g0*8]);
      }
    }
    __syncthreads();
    short8 af = *(short8*)&sA[(wv*16 + l15)*40 + quad*8];
    #pragma unroll
    for (int ct = 0; ct < 32; ++ct) {
      int n = ct*16 + l15;
      int gidx = n*4 + (quad ^ ((n>>2)&3));
      short8 bf = *(short8*)&sB[gidx*8];
      acc[ct] = __builtin_amdgcn_mfma_f32_16x16x32_bf16(af, bf, acc[ct], 0, 0, 0);
    }
  }

  f32x4 p = zero4, q = zero4;
  #pragma unroll
  for (int ct = 0; ct < 32; ++ct) {
    f32x4 t = __builtin_elementwise_max(acc[ct] + splat4(sb[ct*16 + l15]), zero4);
    acc[ct] = t;
    p += t;
    q += t * t;
  }
  #pragma unroll
  for (int i = 0; i < 4; ++i) {
    p[i] = dpp16sum(p[i]);
    q[i] = dpp16sum(q[i]);
  }
  f32x4 mu4  = p * splat4(1.f/512.f);
  f32x4 var4 = __builtin_elementwise_max(q * splat4(1.f/512.f) - mu4*mu4, zero4);
  f32x4 uu, vv;
  #pragma unroll
  for (int i = 0; i < 4; ++i) {
    float inv = fast_rsqrt(var4[i] + LN_EPS);
    uu[i] = inv; vv[i] = -mu4[i]*inv;
  }
  const int row0 = rbase + wv*16 + quad*4;
  #pragma unroll
  for (int ct = 0; ct < 32; ++ct) {
    int gcol = ct*16 + l15;
    f32x4 v = acc[ct]*uu + vv;
    v = splat4(sg[gcol])*v + splat4(sbe[gcol]);
    #pragma unroll
    for (int i = 0; i < 4; ++i) {
      int grow = row0 + i;
      if (grow < nrows)
        out[(size_t)grow*512 + gcol] = v[i];
    }
  }
}

// ---------------------------------------------------------------------------
// K4: res layer, fused residue-max A-staging + async B staging.
// grid: (ceil(R/64), 2), block 256.
// ---------------------------------------------------------------------------
__global__ __launch_bounds__(256) void gemm_ln_res_kernel(
    const float* __restrict__ ax_A, const float* __restrict__ ax_B,
    const unsigned short* __restrict__ wp,
    const float* __restrict__ b, const float* __restrict__ g,
    const float* __restrict__ be,
    float* __restrict__ out_A, float* __restrict__ out_B)
{
  const float* __restrict__ ax = blockIdx.y ? ax_B : ax_A;
  float* __restrict__ out = blockIdx.y ? out_B : out_A;

  __shared__ __align__(16) unsigned short sA[64*40];    // 5 KB
  __shared__ __align__(16) unsigned short sB[512*32];   // 32 KB
  __shared__ float sb[512], sg[512], sbe[512];          // 6 KB

  const int tid  = threadIdx.x;
  const int wv   = tid >> 6;
  const int lane = tid & 63;
  const int l15  = lane & 15;
  const int quad = lane >> 4;
  const int rbase = blockIdx.x * 64;

  sb[tid]      = b[tid];    sb[tid+256]  = b[tid+256];
  sg[tid]      = g[tid];    sg[tid+256]  = g[tid+256];
  sbe[tid]     = be[tid];   sbe[tid+256] = be[tid+256];

  const f32x4 zero4 = splat4(0.f);
  f32x4 acc[32];
  #pragma unroll
  for (int ct = 0; ct < 32; ++ct) acc[ct] = zero4;

  const int arow = tid >> 2, apart = tid & 3;
  int rres = rbase + arow; if (rres >= R_RES) rres = R_RES - 1;
  const float* abase = ax + (size_t)rres*8*512 + apart*8;

  for (int kc = 0; kc < 16; ++kc) {
    __syncthreads();
    {
      const float* ap = abase + kc*32;
      float4 m0 = *(const float4*)(ap);
      float4 m1 = *(const float4*)(ap + 4);
      #pragma unroll
      for (int a = 1; a < 8; ++a) {
        float4 v0 = *(const float4*)(ap + (size_t)a*512);
        float4 v1 = *(const float4*)(ap + (size_t)a*512 + 4);
        m0.x = fmaxf(m0.x, v0.x); m0.y = fmaxf(m0.y, v0.y);
        m0.z = fmaxf(m0.z, v0.z); m0.w = fmaxf(m0.w, v0.w);
        m1.x = fmaxf(m1.x, v1.x); m1.y = fmaxf(m1.y, v1.y);
        m1.z = fmaxf(m1.z, v1.z); m1.w = fmaxf(m1.w, v1.w);
      }
      ushort4 o0, o1;
      o0.x = f2bf(m0.x); o0.y = f2bf(m0.y); o0.z = f2bf(m0.z); o0.w = f2bf(m0.w);
      o1.x = f2bf(m1.x); o1.y = f2bf(m1.y); o1.z = f2bf(m1.z); o1.w = f2bf(m1.w);
      *(ushort4*)&sA[arow*40 + apart*8]     = o0;
      *(ushort4*)&sA[arow*40 + apart*8 + 4] = o1;
    }
    {
      const unsigned short* wsrc = wp + (size_t)kc*16384;
      #pragma unroll
      for (int i = 0; i < 8; ++i) {
        int g0 = (wv*8 + i)*64;
        load_lds_16B(wsrc + (size_t)(g0 + lane)*8, &sB[g0*8]);
      }
    }
    __syncthreads();
    short8 af = *(short8*)&sA[(wv*16 + l15)*40 + quad*8];
    #pragma unroll
    for (int ct = 0; ct < 32; ++ct) {
      int n = ct*16 + l15;
      int gidx = n*4 + (quad ^ ((n>>2)&3));
      short8 bf = *(short8*)&sB[gidx*8];
      acc[ct] = __builtin_amdgcn_mfma_f32_16x16x32_bf16(af, bf, acc[ct], 0, 0, 0);
    }
  }

  f32x4 p = zero4, q = zero4;
  #pragma unroll
  for (int ct = 0; ct < 32; ++ct) {
    f32x4 t = __builtin_elementwise_max(acc[ct] + splat4(sb[ct*16 + l15]), zero4);
    acc[ct] = t;
    p += t;
    q += t * t;
  }
  #pragma unroll
  for (int i = 0; i < 4; ++i) {
    p[i] = dpp16sum(p[i]);
    q[i] = dpp16sum(q[i]);
  }
  f32x4 mu4  = p * splat4(1.f/512.f);
  f32x4 var4 = __builtin_elementwise_max(q * splat4(1.f/512.f) - mu4*mu4, zero4);
  f32x4 uu, vv;
  #pragma unroll
  for (int i = 0; i < 4; ++i) {
    float inv = fast_rsqrt(var4[i] + LN_EPS);
    uu[i] = inv; vv[i] = -mu4[i]*inv;
  }
  const int row0 = rbase + wv*16 + quad*4;
  #pragma unroll
  for (int ct = 0; ct < 32; ++ct) {
    int gcol = ct*16 + l15;
    f32x4 v = acc[ct]*uu + vv;
    v = splat4(sg[gcol])*v + splat4(sbe[gcol]);
    #pragma unroll
    for (int i = 0; i < 4; ++i) {
      int grow = row0 + i;
      if (grow < R_RES)
        out[(size_t)grow*512 + gcol] = v[i];
    }
  }
}

// ---------------------------------------------------------------------------
// K5: out[p] = sigmoid((resx_A[src[p]] - resx_B[tgt[p]]) . lin_w + b)
// 8 lanes per pair (128 blocks).
// ---------------------------------------------------------------------------
__global__ __launch_bounds__(256) void final_kernel(
    const float* __restrict__ resx_A, const float* __restrict__ resx_B,
    const int* __restrict__ src_idx, const int* __restrict__ tgt_idx,
    const float* __restrict__ lin_w, const float* __restrict__ lin_b,
    float* __restrict__ outp)
{
  int idx = blockIdx.x*256 + threadIdx.x;
  int p  = idx >> 3;
  int l8 = idx & 7;
  if (p >= P_PAIRS) return;
  const float4* xa = (const float4*)(resx_A + (size_t)src_idx[p]*512) + l8;
  const float4* xb = (const float4*)(resx_B + (size_t)tgt_idx[p]*512) + l8;
  const float4* wv = (const float4*)lin_w + l8;
  float acc = 0.f;
  #pragma unroll
  for (int i = 0; i < 16; ++i) {
    float4 a = xa[i*8], b = xb[i*8], w = wv[i*8];
    acc += (a.x-b.x)*w.x + (a.y-b.y)*w.y + (a.z-b.z)*w.z + (a.w-b.w)*w.w;
  }
  acc += __shfl_xor(acc, 1, 64);
  acc += __shfl_xor(acc, 2, 64);
  acc += __shfl_xor(acc, 4, 64);
  if (l8 == 0) {
    acc += lin_b[0];
    outp[p] = 1.f/(1.f + expf(-acc));
  }
}

extern "C" void kernel_launch(void* const* d_in, const int* in_sizes, int n_in,
                              void* d_out, int out_size, void* d_ws, size_t ws_size,
                              hipStream_t stream)
{
  const float* pos_A   = (const float*)d_in[0];
  const float* nrm_A   = (const float*)d_in[1];
  const float* pos_B   = (const float*)d_in[2];
  const float* nrm_B   = (const float*)d_in[3];
  const int*   edges_A = (const int*)d_in[4];
  const int*   edges_B = (const int*)d_in[5];
  const int*   src_idx = (const int*)d_in[8];
  const int*   tgt_idx = (const int*)d_in[9];
  const float* conv_w1  = (const float*)d_in[11];
  const float* conv_b1  = (const float*)d_in[12];
  const float* conv_g1  = (const float*)d_in[13];
  const float* conv_be1 = (const float*)d_in[14];
  const float* conv_w2  = (const float*)d_in[15];
  const float* conv_b2  = (const float*)d_in[16];
  const float* conv_g2  = (const float*)d_in[17];
  const float* conv_be2 = (const float*)d_in[18];
  const float* atom_w   = (const float*)d_in[19];
  const float* atom_b   = (const float*)d_in[20];
  const float* atom_g   = (const float*)d_in[21];
  const float* atom_be  = (const float*)d_in[22];
  const float* res_w    = (const float*)d_in[23];
  const float* res_b    = (const float*)d_in[24];
  const float* res_g    = (const float*)d_in[25];
  const float* res_be   = (const float*)d_in[26];
  const float* lin1_w   = (const float*)d_in[27];
  const float* lin1_b   = (const float*)d_in[28];

  unsigned short* feats_A = (unsigned short*)d_ws;                 // 12000*384 bf16
  unsigned short* feats_B = feats_A + (size_t)N_ATOMS*384;
  float* atomx_A = (float*)(feats_B + (size_t)N_ATOMS*384);        // 12000*512 f32
  float* atomx_B = atomx_A + (size_t)N_ATOMS*512;
  float* resx_A  = atomx_B + (size_t)N_ATOMS*512;                  // 1500*512 f32
  float* resx_B  = resx_A + (size_t)R_RES*512;
  unsigned short* wpA = (unsigned short*)(resx_B + (size_t)R_RES*512); // 12*16384 bf16
  unsigned short* wpB = wpA + (size_t)384*512;                         // 16*16384 bf16

  wpack_kernel<<<(384*512)/256, 256, 0, stream>>>(atom_w, wpA, 384);
  wpack_kernel<<<(512*512)/256, 256, 0, stream>>>(res_w, wpB, 512);

  dim3 gG(N_ATOMS/32, 3, 2);
  edge_fused_kernel<<<gG, 256, 0, stream>>>(pos_A, nrm_A, pos_B, nrm_B,
      edges_A, edges_B,
      conv_w1, conv_b1, conv_g1, conv_be1,
      conv_w2, conv_b2, conv_g2, conv_be2,
      feats_A, feats_B);

  dim3 gAtom((N_ATOMS + 63)/64, 2);
  gemm_ln_kernel<<<gAtom, 256, 0, stream>>>(feats_A, feats_B, wpA,
      atom_b, atom_g, atom_be, atomx_A, atomx_B, N_ATOMS, 384);

  dim3 gRes((R_RES + 63)/64, 2);
  gemm_ln_res_kernel<<<gRes, 256, 0, stream>>>(atomx_A, atomx_B, wpB,
      res_b, res_g, res_be, resx_A, resx_B);

  final_kernel<<<(P_PAIRS*8 + 255)/256, 256, 0, stream>>>(resx_A, resx_B,
      src_idx, tgt_idx, lin1_w, lin1_b, (float*)d_out);
}